// Round 1
// baseline (192.548 us; speedup 1.0000x reference)
//
#include <hip/hip_runtime.h>
#include <hip/hip_bf16.h>

// Problem constants
#define BB 2
#define SS 2048
#define DD 1024
#define HH 16
#define HDD 64
#define MM (BB*SS)          // 4096
#define NQKV (3*DD)         // 3072
#define SCALE 0.125f        // HD^-0.5
#define QPRESCALE 0.18033688f   // SCALE * log2(e), folded into Q at GEMM epilogue

typedef __bf16 bf16_t;
typedef bf16_t bf16x4 __attribute__((ext_vector_type(4)));
typedef bf16_t bf16x8 __attribute__((ext_vector_type(8)));
typedef float f32x4 __attribute__((ext_vector_type(4)));
typedef float f32x16 __attribute__((ext_vector_type(16)));

// ---------------------------------------------------------------------------
// global -> LDS direct DMA, 16B per lane.
// ---------------------------------------------------------------------------
__device__ __forceinline__ void gl_lds16(const bf16_t* g, bf16_t* l) {
    __builtin_amdgcn_global_load_lds(
        (const __attribute__((address_space(1))) unsigned int*)(uintptr_t)g,
        (__attribute__((address_space(3))) unsigned int*)(uintptr_t)l,
        16, 0, 0);
}

__device__ __forceinline__ f32x4 MF(bf16x8 a, bf16x8 b, f32x4 c) {
    return __builtin_amdgcn_mfma_f32_16x16x32_bf16(a, b, c, 0, 0, 0);
}

// ---------------------------------------------------------------------------
// Fused prep kernel (one launch):
//   blocks [0,2048): convert x f32 -> bf16 (8 elems/thread)
//   blocks [2048,5120): transpose Wqkv -> wqkvt [3072][1024] bf16 (96x32 tiles)
//   blocks [5120,6144): transpose Wproj -> wprojt [1024][1024] bf16 (32x32 tiles)
// ---------------------------------------------------------------------------
__global__ __launch_bounds__(256) void prep(
    const float* __restrict__ x, const float* __restrict__ Wqkv,
    const float* __restrict__ Wproj, bf16_t* __restrict__ xb,
    bf16_t* __restrict__ wqkvt, bf16_t* __restrict__ wprojt)
{
    const int bx = blockIdx.x;
    if (bx < 2048) {
        int i = (bx * 256 + threadIdx.x) * 8;
        float4 a = *(const float4*)(x + i);
        float4 b = *(const float4*)(x + i + 4);
        bf16x8 v;
        v[0]=(bf16_t)a.x; v[1]=(bf16_t)a.y; v[2]=(bf16_t)a.z; v[3]=(bf16_t)a.w;
        v[4]=(bf16_t)b.x; v[5]=(bf16_t)b.y; v[6]=(bf16_t)b.z; v[7]=(bf16_t)b.w;
        *reinterpret_cast<bf16x8*>(xb + i) = v;
        return;
    }
    __shared__ float tile[32][33];
    const float* src; bf16_t* dst; int C, bxl, byl;
    if (bx < 5120) {
        int t = bx - 2048;
        byl = t / 96; bxl = t - byl * 96;   // 96 not pow2 -> real division
        src = Wqkv;  dst = wqkvt;  C = NQKV;
    } else {
        int t = bx - 5120;
        byl = t >> 5; bxl = t & 31;
        src = Wproj; dst = wprojt; C = DD;
    }
    const int R = DD;
    const int tx = threadIdx.x & 31, ty = threadIdx.x >> 5;
    const int r0 = byl * 32, c0 = bxl * 32;
    #pragma unroll
    for (int i = 0; i < 32; i += 8)
        tile[ty + i][tx] = src[(size_t)(r0 + ty + i) * C + c0 + tx];
    __syncthreads();
    #pragma unroll
    for (int i = 0; i < 32; i += 8)
        dst[(size_t)(c0 + ty + i) * R + r0 + tx] = (bf16_t)tile[tx][ty + i];
}

// ---------------------------------------------------------------------------
// QKV GEMM, 8-phase-style schedule (learn_hip m201/m248 structure):
//   BM=256, BN=192, BK=64, 512 threads = 8 waves (2M x 4N), grid 16x16 = 256
//   blocks = exactly 1/CU (LDS 112KB -> 1 block/CU anyway).
//   - chunk-XOR LDS swizzle (cc ^= row&7) via pre-swizzled global source +
//     swizzled ds_read address (gl_lds dest stays linear).
//   - raw s_barrier (no vmcnt drain), setprio(1) around MFMA clusters,
//     sched_barrier(0) pins the clusters.
//   - tile t+1 staged during phases 0-1 of tile t; single vmcnt(0) at the
//     tile boundary (only the 7 prefetch loads outstanding, >=2 phases of
//     compute cover their latency).
//   Epilogue: QKV scatter + bias + Q prescale (logic identical to previous).
// ---------------------------------------------------------------------------
__global__ __launch_bounds__(512, 2) void gemm_qkv(
    const bf16_t* __restrict__ A, const bf16_t* __restrict__ Bt,
    const float* __restrict__ bias,
    bf16_t* __restrict__ qw, bf16_t* __restrict__ kw, bf16_t* __restrict__ vtw)
{
    constexpr int K  = DD;          // 1024
    constexpr int BM = 256, BN = 192, BK = 64;
    constexpr int NT = K / BK;      // 16

    __shared__ __align__(16) bf16_t smem[2 * BM * BK + 2 * BN * BK]; // 57344 el = 112KB
    bf16_t* const As0 = smem;
    bf16_t* const As1 = smem + BM * BK;            // +16384
    bf16_t* const Bs0 = smem + 2 * BM * BK;        // +32768
    bf16_t* const Bs1 = Bs0 + BN * BK;             // +12288

    const int tid  = threadIdx.x;
    const int w    = tid >> 6;
    const int lane = tid & 63;
    const int lr   = lane & 15;
    const int quad = lane >> 4;
    const int wm   = w >> 2;        // 0..1 -> rows wm*128..+127
    const int wn   = w & 3;         // 0..3 -> cols wn*48..+47
    const int m0   = blockIdx.y * BM;
    const int n0   = blockIdx.x * BN;

    // swizzle: logical chunk (row, cc) lives at LDS chunk (row, cc ^ (row&7)).
    // For frag reads row & 7 == lr & 7 (all row bases are multiples of 8/16).
    const int sx   = lr & 7;
    const int ecc0 = ((quad)     ^ sx) * 8;   // ks=0 element offset within row
    const int ecc1 = ((quad + 4) ^ sx) * 8;   // ks=1
    const int aOff = (wm * 128 + lr) * BK;    // element offset of A row base
    const int bOff = (wn * 48  + lr) * BK;    // element offset of B row base

    f32x4 acc[2][4][3];
    #pragma unroll
    for (int mh = 0; mh < 2; mh++)
        #pragma unroll
        for (int mi = 0; mi < 4; mi++)
            #pragma unroll
            for (int ni = 0; ni < 3; ni++)
                acc[mh][mi][ni] = (f32x4){0.f, 0.f, 0.f, 0.f};

    // cooperative staging with pre-swizzled SOURCE address (rule 21):
    // LDS chunk c gets global chunk (row = c>>3, cc = (c&7) ^ (row&7)).
    auto stageA = [&](int kt, bf16_t* dst) {
        #pragma unroll
        for (int r = 0; r < 4; ++r) {
            const int c   = r * 512 + tid;          // 0..2047
            const int row = c >> 3;
            const int cg  = (c & 7) ^ (row & 7);
            gl_lds16(A + (size_t)(m0 + row) * K + kt * BK + cg * 8, dst + c * 8);
        }
    };
    auto stageB = [&](int kt, bf16_t* dst) {
        #pragma unroll
        for (int r = 0; r < 3; ++r) {
            const int c   = r * 512 + tid;          // 0..1535
            const int row = c >> 3;
            const int cg  = (c & 7) ^ (row & 7);
            gl_lds16(Bt + (size_t)(n0 + row) * K + kt * BK + cg * 8, dst + c * 8);
        }
    };

    // prologue: stage tile 0, drain, barrier
    stageA(0, As0);
    stageB(0, Bs0);
    asm volatile("s_waitcnt vmcnt(0)" ::: "memory");
    __builtin_amdgcn_s_barrier();

    auto tile = [&](int t, const bf16_t* Ac, const bf16_t* Bc,
                    bf16_t* An, bf16_t* Bn) {
        const bool more = (t + 1) < NT;
        bf16x8 af[4], bk0[3], bk1[3];

        // ---- phase 0: (mh=0, ks=0); issue A prefetch of tile t+1
        #pragma unroll
        for (int mi = 0; mi < 4; mi++)
            af[mi] = *(const bf16x8*)(Ac + aOff + mi * 16 * BK + ecc0);
        #pragma unroll
        for (int ni = 0; ni < 3; ni++)
            bk0[ni] = *(const bf16x8*)(Bc + bOff + ni * 16 * BK + ecc0);
        if (more) stageA(t + 1, An);
        __builtin_amdgcn_s_barrier();
        __builtin_amdgcn_sched_barrier(0);
        __builtin_amdgcn_s_setprio(1);
        #pragma unroll
        for (int mi = 0; mi < 4; mi++)
            #pragma unroll
            for (int ni = 0; ni < 3; ni++)
                acc[0][mi][ni] = MF(af[mi], bk0[ni], acc[0][mi][ni]);
        __builtin_amdgcn_s_setprio(0);
        __builtin_amdgcn_sched_barrier(0);
        __builtin_amdgcn_s_barrier();

        // ---- phase 1: (mh=0, ks=1); issue B prefetch of tile t+1
        #pragma unroll
        for (int mi = 0; mi < 4; mi++)
            af[mi] = *(const bf16x8*)(Ac + aOff + mi * 16 * BK + ecc1);
        #pragma unroll
        for (int ni = 0; ni < 3; ni++)
            bk1[ni] = *(const bf16x8*)(Bc + bOff + ni * 16 * BK + ecc1);
        if (more) stageB(t + 1, Bn);
        __builtin_amdgcn_s_barrier();
        __builtin_amdgcn_sched_barrier(0);
        __builtin_amdgcn_s_setprio(1);
        #pragma unroll
        for (int mi = 0; mi < 4; mi++)
            #pragma unroll
            for (int ni = 0; ni < 3; ni++)
                acc[0][mi][ni] = MF(af[mi], bk1[ni], acc[0][mi][ni]);
        __builtin_amdgcn_s_setprio(0);
        __builtin_amdgcn_sched_barrier(0);
        __builtin_amdgcn_s_barrier();

        // ---- phase 2: (mh=1, ks=1); reuse bk1
        #pragma unroll
        for (int mi = 0; mi < 4; mi++)
            af[mi] = *(const bf16x8*)(Ac + aOff + (64 + mi * 16) * BK + ecc1);
        __builtin_amdgcn_s_barrier();
        __builtin_amdgcn_sched_barrier(0);
        __builtin_amdgcn_s_setprio(1);
        #pragma unroll
        for (int mi = 0; mi < 4; mi++)
            #pragma unroll
            for (int ni = 0; ni < 3; ni++)
                acc[1][mi][ni] = MF(af[mi], bk1[ni], acc[1][mi][ni]);
        __builtin_amdgcn_s_setprio(0);
        __builtin_amdgcn_sched_barrier(0);
        __builtin_amdgcn_s_barrier();

        // ---- phase 3: (mh=1, ks=0); reuse bk0; tile-boundary counted drain
        #pragma unroll
        for (int mi = 0; mi < 4; mi++)
            af[mi] = *(const bf16x8*)(Ac + aOff + (64 + mi * 16) * BK + ecc0);
        __builtin_amdgcn_s_barrier();
        __builtin_amdgcn_sched_barrier(0);
        __builtin_amdgcn_s_setprio(1);
        #pragma unroll
        for (int mi = 0; mi < 4; mi++)
            #pragma unroll
            for (int ni = 0; ni < 3; ni++)
                acc[1][mi][ni] = MF(af[mi], bk0[ni], acc[1][mi][ni]);
        __builtin_amdgcn_s_setprio(0);
        __builtin_amdgcn_sched_barrier(0);
        if (more) asm volatile("s_waitcnt vmcnt(0)" ::: "memory");
        __builtin_amdgcn_s_barrier();
    };

    #pragma unroll 1
    for (int tt = 0; tt < NT; tt += 2) {
        tile(tt,     As0, Bs0, As1, Bs1);
        tile(tt + 1, As1, Bs1, As0, Bs0);
    }

    // epilogue: scatter to q / k / v^T with bias (+ Q prescale)
    #pragma unroll
    for (int mh = 0; mh < 2; mh++) {
        #pragma unroll
        for (int mi = 0; mi < 4; mi++) {
            #pragma unroll
            for (int ni = 0; ni < 3; ni++) {
                const int col = n0 + wn * 48 + ni * 16 + lr;
                const float bcol = bias[col];
                const int which = col >> 10;
                const int d = col & 1023;
                const int h = d >> 6, hd = d & 63;
                #pragma unroll
                for (int reg = 0; reg < 4; reg++) {
                    const int row = m0 + wm * 128 + mh * 64 + mi * 16 + quad * 4 + reg;
                    const float val = acc[mh][mi][ni][reg] + bcol;
                    const int b = row >> 11, s = row & 2047;
                    const size_t bh = (size_t)(b * HH + h);
                    if (which == 0)      qw[(bh * SS + s) * HDD + hd] = (bf16_t)(val * QPRESCALE);
                    else if (which == 1) kw[(bh * SS + s) * HDD + hd] = (bf16_t)val;
                    else                 vtw[(bh * HDD + hd) * SS + s] = (bf16_t)val;
                }
            }
        }
    }
}

// ---------------------------------------------------------------------------
// BM=64 proj GEMM, BK=64 (grid 512 = 2/CU). Unchanged this round.
// ---------------------------------------------------------------------------
__global__ __launch_bounds__(256) void gemm_bt64(
    const bf16_t* __restrict__ A, const bf16_t* __restrict__ Bt,
    const float* __restrict__ bias, float* __restrict__ outf, int N, int K)
{
    __shared__ __align__(16) bf16_t As[2][64 * 32];
    __shared__ __align__(16) bf16_t Bs[2][128 * 32];

    const int tid  = threadIdx.x;
    const int w    = tid >> 6;
    const int lane = tid & 63;
    const int lr   = lane & 15;
    const int quad = lane >> 4;
    const int m0   = blockIdx.y * 64;
    const int n0   = blockIdx.x * 128;
    const int wm   = w >> 1;
    const int wn   = w & 1;

    f32x4 acc[2][4];
    #pragma unroll
    for (int i = 0; i < 2; i++)
        #pragma unroll
        for (int j = 0; j < 4; j++) acc[i][j] = (f32x4){0.f, 0.f, 0.f, 0.f};

    const int stgRow = lane >> 2;
    const int stgCol = (lane & 3) * 8;
    const bf16_t* aPtr = A  + (size_t)(m0 + w * 16 + stgRow) * K + stgCol;
    const bf16_t* bPtr = Bt + (size_t)(n0 + w * 32 + stgRow) * K + stgCol;
    const size_t rowSkip = (size_t)16 * K;

    for (int ks = 0; ks < K; ks += 64) {
        __syncthreads();
        #pragma unroll
        for (int s = 0; s < 2; s++) {
            const int ko = ks + s * 32;
            gl_lds16(aPtr + ko,           &As[s][w * 512]);
            gl_lds16(bPtr + ko,           &Bs[s][w * 1024]);
            gl_lds16(bPtr + rowSkip + ko, &Bs[s][w * 1024 + 512]);
        }
        __syncthreads();

        #pragma unroll
        for (int s = 0; s < 2; s++) {
            bf16x8 af[2], bf[4];
            #pragma unroll
            for (int mi = 0; mi < 2; mi++)
                af[mi] = *reinterpret_cast<const bf16x8*>(&As[s][(wm * 32 + mi * 16 + lr) * 32 + quad * 8]);
            #pragma unroll
            for (int ni = 0; ni < 4; ni++)
                bf[ni] = *reinterpret_cast<const bf16x8*>(&Bs[s][(wn * 64 + ni * 16 + lr) * 32 + quad * 8]);
            #pragma unroll
            for (int mi = 0; mi < 2; mi++)
                #pragma unroll
                for (int ni = 0; ni < 4; ni++)
                    acc[mi][ni] = __builtin_amdgcn_mfma_f32_16x16x32_bf16(af[mi], bf[ni], acc[mi][ni], 0, 0, 0);
        }
    }

    #pragma unroll
    for (int mi = 0; mi < 2; mi++)
        #pragma unroll
        for (int ni = 0; ni < 4; ni++)
            #pragma unroll
            for (int reg = 0; reg < 4; reg++) {
                int row = m0 + wm * 32 + mi * 16 + quad * 4 + reg;
                int col = n0 + wn * 64 + ni * 16 + lr;
                outf[(size_t)row * N + col] = acc[mi][ni][reg] + bias[col];
            }
}

// ---------------------------------------------------------------------------
// Flash attention v8 (unchanged): 32x32x16, 2-way kv-split,
// register P, double-buffered K/V LDS -> one barrier/iter.
// ---------------------------------------------------------------------------
__global__ __launch_bounds__(512, 4) void attn_kernel(
    const bf16_t* __restrict__ qws, const bf16_t* __restrict__ kws,
    const bf16_t* __restrict__ vtws, bf16_t* __restrict__ ob)
{
    __shared__ __align__(16) bf16_t smem[34048];
    bf16_t* Ks = smem;
    bf16_t* Vs = smem + 16640;

    const int tid  = threadIdx.x;
    const int w    = tid >> 6;
    const int g    = w >> 2;
    const int wg   = w & 3;
    const int lane = tid & 63;
    const int ln31 = lane & 31;
    const int ln5  = lane >> 5;

    const int qb = blockIdx.x;
    const int bh = blockIdx.y;
    const int b  = bh >> 4;
    const int h  = bh & 15;

    const bf16_t* Qh  = qws  + (size_t)bh * SS * HDD;
    const bf16_t* Kh  = kws  + (size_t)bh * SS * HDD;
    const bf16_t* Vth = vtws + (size_t)bh * HDD * SS;

    const int q0w    = qb * 128 + wg * 32;
    const int kvbase = g * 1024;

    bf16x8 aq[4];
    #pragma unroll
    for (int f = 0; f < 4; f++)
        aq[f] = *(const bf16x8*)(Qh + (size_t)(q0w + ln31) * HDD + f * 16 + ln5 * 8);

    const int gtid = tid & 255;
    const int sc = gtid & 7;
    const int sr = gtid >> 3;

    {
        const int ko = g * 520;
        const int vo = g * 4352;
        bf16x8 k0 = *(const bf16x8*)(Kh  + (size_t)(kvbase + sr     ) * HDD + sc * 8);
        bf16x8 k1 = *(const bf16x8*)(Kh  + (size_t)(kvbase + sr + 32) * HDD + sc * 8);
        bf16x8 v0 = *(const bf16x8*)(Vth + (size_t)(sr     ) * SS + kvbase + sc * 8);
        bf16x8 v1 = *(const bf16x8*)(Vth + (size_t)(sr + 32) * SS + kvbase + sc * 8);
        *reinterpret_cast<bf16x8*>(&Ks[(ko + sc * 65 + sr     ) * 8]) = k0;
        *reinterpret_cast<bf16x8*>(&Ks[(ko + sc * 65 + sr + 32) * 8]) = k1;
        bf16_t* vd0 = &Vs[vo + (sr     ) * 68 + sc * 8];
        bf16_t* vd1 = &Vs[vo + (sr + 32) * 68 + sc * 8];
        *reinterpret_cast<bf16x4*>(vd0)     = __builtin_shufflevector(v0, v0, 0,1,2,3);
        *reinterpret_cast<bf16x4*>(vd0 + 4) = __builtin_shufflevector(v0, v0, 4,5,6,7);
        *reinterpret_cast<bf16x4*>(vd1)     = __builtin_shufflevector(v1, v1, 0,1,2,3);
        *reinterpret_cast<bf16x4*>(vd1 + 4) = __builtin_shufflevector(v1, v1, 4,5,6,7);
    }
    __syncthreads();

    float l = 0.f;
    f32x16 o[2];
    #pragma unroll
    for (int nh = 0; nh < 2; nh++)
        #pragma unroll
        for (int r = 0; r < 16; r++) o[nh][r] = 0.f;

    int buf = 0;
    for (int it = 0; it < 16; ++it) {
        const int ko = buf * 1040 + g * 520;
        const int vo = buf * 8704 + g * 4352;

        f32x16 sfr[2];
        #pragma unroll
        for (int ni = 0; ni < 2; ni++) {
            #pragma unroll
            for (int r = 0; r < 16; r++) sfr[ni][r] = 0.f;
            #pragma unroll
            for (int f = 0; f < 4; f++) {
                bf16x8 kb = *reinterpret_cast<const bf16x8*>(
                    &Ks[(ko + (2 * f + ln5) * 65 + ni * 32 + ln31) * 8]);
                sfr[ni] = __builtin_amdgcn_mfma_f32_32x32x16_bf16(kb, aq[f], sfr[ni], 0, 0, 0);
            }
        }

        bf16x8 nk0, nk1, nv0, nv1;
        const bool more = (it + 1 < 16);
        if (more) {
            const int kvn = kvbase + (it + 1) * 64;
            nk0 = *(const bf16x8*)(Kh  + (size_t)(kvn + sr     ) * HDD + sc * 8);
            nk1 = *(const bf16x8*)(Kh  + (size_t)(kvn + sr + 32) * HDD + sc * 8);
            nv0 = *(const bf16x8*)(Vth + (size_t)(sr     ) * SS + kvn + sc * 8);
            nv1 = *(const bf16x8*)(Vth + (size_t)(sr + 32) * SS + kvn + sc * 8);
        }

        float p[2][16];
        #pragma unroll
        for (int ni = 0; ni < 2; ni++)
            #pragma unroll
            for (int r = 0; r < 16; r++) {
                p[ni][r] = __builtin_amdgcn_exp2f(sfr[ni][r]);
                l += p[ni][r];
            }

        bf16x8 ap[4];
        #pragma unroll
        for (int c16 = 0; c16 < 4; c16++)
            #pragma unroll
            for (int j = 0; j < 8; j++)
                ap[c16][j] = (bf16_t)p[c16 >> 1][(c16 & 1) * 8 + j];

        #pragma unroll
        for (int nh = 0; nh < 2; nh++) {
            const bf16_t* vrow = &Vs[vo + (nh * 32 + ln31) * 68];
            #pragma unroll
            for (int c16 = 0; c16 < 4; c16++) {
                bf16x4 lo = *(const bf16x4*)(vrow + c16 * 16 + 4 * ln5);
                bf16x4 hi = *(const bf16x4*)(vrow + c16 * 16 + 8 + 4 * ln5);
                bf16x8 vb = __builtin_shufflevector(lo, hi, 0, 1, 2, 3, 4, 5, 6, 7);
                o[nh] = __builtin_amdgcn_mfma_f32_32x32x16_bf16(ap[c16], vb, o[nh], 0, 0, 0);
            }
        }

        if (more) {
            const int ko1 = (buf ^ 1) * 1040 + g * 520;
            const int vo1 = (buf ^ 1) * 8704 + g * 4352;
            *reinterpret_cast<bf16x8*>(&Ks[(ko1 + sc * 65 + sr     ) * 8]) = nk0;
            *reinterpret_cast<bf16x8*>(&Ks[(ko1 + sc * 65 + sr + 32) * 8]) = nk1;
            bf16_t* vd0 = &Vs[vo1 + (sr     ) * 68 + sc * 8];
            bf16_t* vd1 = &Vs[vo1 + (sr + 32) * 68 + sc * 8];
            *reinterpret_cast<bf16x4*>(vd0)     = __builtin_shufflevector(nv0, nv0, 0,1,2,3);
            *reinterpret_cast<bf16x4*>(vd0 + 4) = __builtin_shufflevector(nv0, nv0, 4,5,6,7);
            *reinterpret_cast<bf16x4*>(vd1)     = __builtin_shufflevector(nv1, nv1, 0,1,2,3);
            *reinterpret_cast<bf16x4*>(vd1 + 4) = __builtin_shufflevector(nv1, nv1, 4,5,6,7);
        }
        __syncthreads();
        buf ^= 1;
    }

    l += __shfl_xor(l, 32, 64);

    __syncthreads();
    float* Of = (float*)smem;
    float* Lf = (float*)(smem + 16384);
    if (ln5 == 0) Lf[g * 128 + wg * 32 + ln31] = l;
    if (g == 1) {
        #pragma unroll
        for (int nh = 0; nh < 2; nh++)
            #pragma unroll
            for (int r = 0; r < 16; r++) {
                const int q = (r & 3) + 8 * (r >> 2) + 4 * ln5;
                Of[(wg * 32 + q) * 64 + nh * 32 + ln31] = o[nh][r];
            }
    }
    __syncthreads();
    if (g == 0) {
        float inv[16];
        #pragma unroll
        for (int r = 0; r < 16; r++) {
            const int q = (r & 3) + 8 * (r >> 2) + 4 * ln5;
            inv[r] = 1.f / (Lf[wg * 32 + q] + Lf[128 + wg * 32 + q]);
        }
        #pragma unroll
        for (int nh = 0; nh < 2; nh++)
            #pragma unroll
            for (int r = 0; r < 16; r++) {
                const int q  = (r & 3) + 8 * (r >> 2) + 4 * ln5;
                const int hd = nh * 32 + ln31;
                float val = (o[nh][r] + Of[(wg * 32 + q) * 64 + hd]) * inv[r];
                ob[((size_t)b * SS + q0w + q) * DD + h * HDD + hd] = (bf16_t)val;
            }
    }
}

// ---------------------------------------------------------------------------
extern "C" void kernel_launch(void* const* d_in, const int* in_sizes, int n_in,
                              void* d_out, int out_size, void* d_ws, size_t ws_size,
                              hipStream_t stream) {
    const float* x     = (const float*)d_in[0];
    const float* Wqkv  = (const float*)d_in[1];
    const float* bqkv  = (const float*)d_in[2];
    const float* Wproj = (const float*)d_in[3];
    const float* bproj = (const float*)d_in[4];
    float* out = (float*)d_out;

    const size_t NEL = (size_t)MM * DD;   // 4194304
    bf16_t* qws    = (bf16_t*)d_ws;
    bf16_t* kws    = qws  + NEL;
    bf16_t* vtws   = kws  + NEL;
    bf16_t* xb     = vtws + NEL;          // aliased: xb then ows
    bf16_t* ows    = xb;
    bf16_t* wqkvt  = xb + NEL;
    bf16_t* wprojt = wqkvt + (size_t)NQKV * DD;

    prep<<<6144, 256, 0, stream>>>(x, Wqkv, Wproj, xb, wqkvt, wprojt);

    gemm_qkv<<<dim3(NQKV / 192, MM / 256), 512, 0, stream>>>(
        xb, wqkvt, bqkv, qws, kws, vtws);

    attn_kernel<<<dim3(SS / 128, BB * HH), 512, 0, stream>>>(qws, kws, vtws, ows);

    gemm_bt64<<<dim3(DD / 128, MM / 64), 256, 0, stream>>>(
        ows, wprojt, bproj, out, DD, DD);
}

// Round 2
// 179.752 us; speedup vs baseline: 1.0712x; 1.0712x over previous
//
#include <hip/hip_runtime.h>
#include <hip/hip_bf16.h>

// Problem constants
#define BB 2
#define SS 2048
#define DD 1024
#define HH 16
#define HDD 64
#define MM (BB*SS)          // 4096
#define NQKV (3*DD)         // 3072
#define SCALE 0.125f        // HD^-0.5
#define QPRESCALE 0.18033688f   // SCALE * log2(e), folded into Q at GEMM epilogue

typedef __bf16 bf16_t;
typedef bf16_t bf16x4 __attribute__((ext_vector_type(4)));
typedef bf16_t bf16x8 __attribute__((ext_vector_type(8)));
typedef float f32x4 __attribute__((ext_vector_type(4)));
typedef float f32x16 __attribute__((ext_vector_type(16)));

// ---------------------------------------------------------------------------
// global -> LDS direct DMA, 16B per lane.
// ---------------------------------------------------------------------------
__device__ __forceinline__ void gl_lds16(const bf16_t* g, bf16_t* l) {
    __builtin_amdgcn_global_load_lds(
        (const __attribute__((address_space(1))) unsigned int*)(uintptr_t)g,
        (__attribute__((address_space(3))) unsigned int*)(uintptr_t)l,
        16, 0, 0);
}

__device__ __forceinline__ f32x4 MF(bf16x8 a, bf16x8 b, f32x4 c) {
    return __builtin_amdgcn_mfma_f32_16x16x32_bf16(a, b, c, 0, 0, 0);
}

// ---------------------------------------------------------------------------
// Fused prep kernel (one launch):
//   blocks [0,2048): convert x f32 -> bf16 (8 elems/thread)
//   blocks [2048,5120): transpose Wqkv -> wqkvt [3072][1024] bf16 (96x32 tiles)
//   blocks [5120,6144): transpose Wproj -> wprojt [1024][1024] bf16 (32x32 tiles)
// ---------------------------------------------------------------------------
__global__ __launch_bounds__(256) void prep(
    const float* __restrict__ x, const float* __restrict__ Wqkv,
    const float* __restrict__ Wproj, bf16_t* __restrict__ xb,
    bf16_t* __restrict__ wqkvt, bf16_t* __restrict__ wprojt)
{
    const int bx = blockIdx.x;
    if (bx < 2048) {
        int i = (bx * 256 + threadIdx.x) * 8;
        float4 a = *(const float4*)(x + i);
        float4 b = *(const float4*)(x + i + 4);
        bf16x8 v;
        v[0]=(bf16_t)a.x; v[1]=(bf16_t)a.y; v[2]=(bf16_t)a.z; v[3]=(bf16_t)a.w;
        v[4]=(bf16_t)b.x; v[5]=(bf16_t)b.y; v[6]=(bf16_t)b.z; v[7]=(bf16_t)b.w;
        *reinterpret_cast<bf16x8*>(xb + i) = v;
        return;
    }
    __shared__ float tile[32][33];
    const float* src; bf16_t* dst; int C, bxl, byl;
    if (bx < 5120) {
        int t = bx - 2048;
        byl = t / 96; bxl = t - byl * 96;   // 96 not pow2 -> real division
        src = Wqkv;  dst = wqkvt;  C = NQKV;
    } else {
        int t = bx - 5120;
        byl = t >> 5; bxl = t & 31;
        src = Wproj; dst = wprojt; C = DD;
    }
    const int R = DD;
    const int tx = threadIdx.x & 31, ty = threadIdx.x >> 5;
    const int r0 = byl * 32, c0 = bxl * 32;
    #pragma unroll
    for (int i = 0; i < 32; i += 8)
        tile[ty + i][tx] = src[(size_t)(r0 + ty + i) * C + c0 + tx];
    __syncthreads();
    #pragma unroll
    for (int i = 0; i < 32; i += 8)
        dst[(size_t)(c0 + ty + i) * R + r0 + tx] = (bf16_t)tile[tx][ty + i];
}

// ---------------------------------------------------------------------------
// QKV GEMM: BM=256, BN=192, BK=64, 512 threads = 8 waves (2M x 4N),
// grid 16x16 = 256 blocks = exactly 1/CU.
// R2 changes vs R1:
//   - 2 phases/tile (24 MFMA each) instead of 4 thin ones; barriers 8 -> 3
//     per tile. All prefetch (A+B of t+1) issued in phase 0; vmcnt(0) at
//     tile end is covered by a full phase (~930 cyc) of MFMA.
//   - V^T epilogue via LDS transpose: ds_write_b64 packed acc rows into a
//     padded [lcol][264] tile, then coalesced 16B global stores along S.
//     (Old path: 2B stores with 64-way address divergence -> ~8 us.)
// ---------------------------------------------------------------------------
__global__ __launch_bounds__(512, 2) void gemm_qkv(
    const bf16_t* __restrict__ A, const bf16_t* __restrict__ Bt,
    const float* __restrict__ bias,
    bf16_t* __restrict__ qw, bf16_t* __restrict__ kw, bf16_t* __restrict__ vtw)
{
    constexpr int K  = DD;          // 1024
    constexpr int BM = 256, BN = 192, BK = 64;
    constexpr int NT = K / BK;      // 16

    __shared__ __align__(16) bf16_t smem[2 * BM * BK + 2 * BN * BK]; // 57344 el = 112KB
    bf16_t* const As0 = smem;
    bf16_t* const As1 = smem + BM * BK;            // +16384
    bf16_t* const Bs0 = smem + 2 * BM * BK;        // +32768
    bf16_t* const Bs1 = Bs0 + BN * BK;             // +12288

    const int tid  = threadIdx.x;
    const int w    = tid >> 6;
    const int lane = tid & 63;
    const int lr   = lane & 15;
    const int quad = lane >> 4;
    const int wm   = w >> 2;        // 0..1 -> rows wm*128..+127
    const int wn   = w & 3;         // 0..3 -> cols wn*48..+47
    const int m0   = blockIdx.y * BM;
    const int n0   = blockIdx.x * BN;

    // swizzle: logical chunk (row, cc) lives at LDS chunk (row, cc ^ (row&7)).
    const int sx   = lr & 7;
    const int ecc0 = ((quad)     ^ sx) * 8;   // ks=0 element offset within row
    const int ecc1 = ((quad + 4) ^ sx) * 8;   // ks=1
    const int aOff = (wm * 128 + lr) * BK;    // element offset of A row base
    const int bOff = (wn * 48  + lr) * BK;    // element offset of B row base

    f32x4 acc[2][4][3];
    #pragma unroll
    for (int mh = 0; mh < 2; mh++)
        #pragma unroll
        for (int mi = 0; mi < 4; mi++)
            #pragma unroll
            for (int ni = 0; ni < 3; ni++)
                acc[mh][mi][ni] = (f32x4){0.f, 0.f, 0.f, 0.f};

    // cooperative staging with pre-swizzled SOURCE address (rule 21):
    // LDS chunk c gets global chunk (row = c>>3, cc = (c&7) ^ (row&7)).
    auto stageA = [&](int kt, bf16_t* dst) {
        #pragma unroll
        for (int r = 0; r < 4; ++r) {
            const int c   = r * 512 + tid;          // 0..2047
            const int row = c >> 3;
            const int cg  = (c & 7) ^ (row & 7);
            gl_lds16(A + (size_t)(m0 + row) * K + kt * BK + cg * 8, dst + c * 8);
        }
    };
    auto stageB = [&](int kt, bf16_t* dst) {
        #pragma unroll
        for (int r = 0; r < 3; ++r) {
            const int c   = r * 512 + tid;          // 0..1535
            const int row = c >> 3;
            const int cg  = (c & 7) ^ (row & 7);
            gl_lds16(Bt + (size_t)(n0 + row) * K + kt * BK + cg * 8, dst + c * 8);
        }
    };

    // prologue: stage tile 0, drain, barrier
    stageA(0, As0);
    stageB(0, Bs0);
    asm volatile("s_waitcnt vmcnt(0)" ::: "memory");
    __builtin_amdgcn_s_barrier();

    auto tile = [&](int t, const bf16_t* Ac, const bf16_t* Bc,
                    bf16_t* An, bf16_t* Bn) {
        const bool more = (t + 1) < NT;
        bf16x8 af[8], bk[3];

        // ---- phase 0: ks=0, both row-halves; issue ALL prefetch for t+1
        #pragma unroll
        for (int mi = 0; mi < 4; mi++) {
            af[mi]     = *(const bf16x8*)(Ac + aOff + mi * 16 * BK + ecc0);
            af[4 + mi] = *(const bf16x8*)(Ac + aOff + (64 + mi * 16) * BK + ecc0);
        }
        #pragma unroll
        for (int ni = 0; ni < 3; ni++)
            bk[ni] = *(const bf16x8*)(Bc + bOff + ni * 16 * BK + ecc0);
        if (more) { stageA(t + 1, An); stageB(t + 1, Bn); }
        __builtin_amdgcn_s_barrier();
        __builtin_amdgcn_sched_barrier(0);
        __builtin_amdgcn_s_setprio(1);
        #pragma unroll
        for (int mh = 0; mh < 2; mh++)
            #pragma unroll
            for (int mi = 0; mi < 4; mi++)
                #pragma unroll
                for (int ni = 0; ni < 3; ni++)
                    acc[mh][mi][ni] = MF(af[mh * 4 + mi], bk[ni], acc[mh][mi][ni]);
        __builtin_amdgcn_s_setprio(0);
        __builtin_amdgcn_sched_barrier(0);

        // ---- phase 1: ks=1 (no barrier needed before these reads: buffers
        // are stable for the whole tile; the phase barrier below re-syncs)
        #pragma unroll
        for (int mi = 0; mi < 4; mi++) {
            af[mi]     = *(const bf16x8*)(Ac + aOff + mi * 16 * BK + ecc1);
            af[4 + mi] = *(const bf16x8*)(Ac + aOff + (64 + mi * 16) * BK + ecc1);
        }
        #pragma unroll
        for (int ni = 0; ni < 3; ni++)
            bk[ni] = *(const bf16x8*)(Bc + bOff + ni * 16 * BK + ecc1);
        __builtin_amdgcn_s_barrier();
        __builtin_amdgcn_sched_barrier(0);
        __builtin_amdgcn_s_setprio(1);
        #pragma unroll
        for (int mh = 0; mh < 2; mh++)
            #pragma unroll
            for (int mi = 0; mi < 4; mi++)
                #pragma unroll
                for (int ni = 0; ni < 3; ni++)
                    acc[mh][mi][ni] = MF(af[mh * 4 + mi], bk[ni], acc[mh][mi][ni]);
        __builtin_amdgcn_s_setprio(0);
        __builtin_amdgcn_sched_barrier(0);
        // tile boundary: own prefetch loads must have landed in all waves
        if (more) asm volatile("s_waitcnt vmcnt(0)" ::: "memory");
        __builtin_amdgcn_s_barrier();
    };

    #pragma unroll 1
    for (int tt = 0; tt < NT; tt += 2) {
        tile(tt,     As0, Bs0, As1, Bs1);
        tile(tt + 1, As1, Bs1, As0, Bs0);
    }

    // ---- epilogue ----------------------------------------------------------
    // barrier: make sure all waves' LDS reads of the last tile are done
    // before we reuse smem as the V-transpose buffer.
    __builtin_amdgcn_s_barrier();

    const int colBase = n0 + wn * 48;
    const int vbase   = (n0 < 2048) ? 2048 : n0;   // first V column this block
    // pass 1: direct q/k stores; V accs -> LDS [lcol][264] (row-padded)
    #pragma unroll
    for (int mh = 0; mh < 2; mh++) {
        #pragma unroll
        for (int ni = 0; ni < 3; ni++) {
            const int col = colBase + ni * 16 + lr;
            const float bcol = bias[col];
            const int which = col >> 10;
            const int d = col & 1023;
            const int h = d >> 6, hd = d & 63;
            #pragma unroll
            for (int mi = 0; mi < 4; mi++) {
                const int rl0 = wm * 128 + mh * 64 + mi * 16 + quad * 4;
                if (which == 0) {
                    #pragma unroll
                    for (int reg = 0; reg < 4; reg++) {
                        const int row = m0 + rl0 + reg;
                        const int b = row >> 11, s = row & 2047;
                        qw[(((size_t)(b * HH + h)) * SS + s) * HDD + hd] =
                            (bf16_t)((acc[mh][mi][ni][reg] + bcol) * QPRESCALE);
                    }
                } else if (which == 1) {
                    #pragma unroll
                    for (int reg = 0; reg < 4; reg++) {
                        const int row = m0 + rl0 + reg;
                        const int b = row >> 11, s = row & 2047;
                        kw[(((size_t)(b * HH + h)) * SS + s) * HDD + hd] =
                            (bf16_t)(acc[mh][mi][ni][reg] + bcol);
                    }
                } else {
                    bf16x4 pk;
                    #pragma unroll
                    for (int reg = 0; reg < 4; reg++)
                        pk[reg] = (bf16_t)(acc[mh][mi][ni][reg] + bcol);
                    const int lc = col - vbase;
                    *reinterpret_cast<bf16x4*>(&smem[lc * 264 + rl0]) = pk;
                }
            }
        }
    }
    // pass 2: coalesced V^T stores (16B along S)
    const int nv = n0 + BN - 2048;
    if (nv > 0) {
        __builtin_amdgcn_s_barrier();
        const int nvc = nv < BN ? nv : BN;
        const int lcb = tid >> 5;            // 0..15
        const int rl  = (tid & 31) * 8;      // 0..248
        const int b   = m0 >> 11;
        const int s   = (m0 & 2047) + rl;
        for (int j = 0; j < nvc / 16; j++) {
            const int lc = j * 16 + lcb;
            bf16x8 vv = *reinterpret_cast<const bf16x8*>(&smem[lc * 264 + rl]);
            const int col = vbase + lc;
            const int d = col & 1023;
            const int h = d >> 6, hd = d & 63;
            *reinterpret_cast<bf16x8*>(
                vtw + (((size_t)(b * HH + h)) * HDD + hd) * SS + s) = vv;
        }
    }
}

// ---------------------------------------------------------------------------
// BM=64 proj GEMM, BK=64 (grid 512 = 2/CU). Unchanged this round.
// ---------------------------------------------------------------------------
__global__ __launch_bounds__(256) void gemm_bt64(
    const bf16_t* __restrict__ A, const bf16_t* __restrict__ Bt,
    const float* __restrict__ bias, float* __restrict__ outf, int N, int K)
{
    __shared__ __align__(16) bf16_t As[2][64 * 32];
    __shared__ __align__(16) bf16_t Bs[2][128 * 32];

    const int tid  = threadIdx.x;
    const int w    = tid >> 6;
    const int lane = tid & 63;
    const int lr   = lane & 15;
    const int quad = lane >> 4;
    const int m0   = blockIdx.y * 64;
    const int n0   = blockIdx.x * 128;
    const int wm   = w >> 1;
    const int wn   = w & 1;

    f32x4 acc[2][4];
    #pragma unroll
    for (int i = 0; i < 2; i++)
        #pragma unroll
        for (int j = 0; j < 4; j++) acc[i][j] = (f32x4){0.f, 0.f, 0.f, 0.f};

    const int stgRow = lane >> 2;
    const int stgCol = (lane & 3) * 8;
    const bf16_t* aPtr = A  + (size_t)(m0 + w * 16 + stgRow) * K + stgCol;
    const bf16_t* bPtr = Bt + (size_t)(n0 + w * 32 + stgRow) * K + stgCol;
    const size_t rowSkip = (size_t)16 * K;

    for (int ks = 0; ks < K; ks += 64) {
        __syncthreads();
        #pragma unroll
        for (int s = 0; s < 2; s++) {
            const int ko = ks + s * 32;
            gl_lds16(aPtr + ko,           &As[s][w * 512]);
            gl_lds16(bPtr + ko,           &Bs[s][w * 1024]);
            gl_lds16(bPtr + rowSkip + ko, &Bs[s][w * 1024 + 512]);
        }
        __syncthreads();

        #pragma unroll
        for (int s = 0; s < 2; s++) {
            bf16x8 af[2], bf[4];
            #pragma unroll
            for (int mi = 0; mi < 2; mi++)
                af[mi] = *reinterpret_cast<const bf16x8*>(&As[s][(wm * 32 + mi * 16 + lr) * 32 + quad * 8]);
            #pragma unroll
            for (int ni = 0; ni < 4; ni++)
                bf[ni] = *reinterpret_cast<const bf16x8*>(&Bs[s][(wn * 64 + ni * 16 + lr) * 32 + quad * 8]);
            #pragma unroll
            for (int mi = 0; mi < 2; mi++)
                #pragma unroll
                for (int ni = 0; ni < 4; ni++)
                    acc[mi][ni] = __builtin_amdgcn_mfma_f32_16x16x32_bf16(af[mi], bf[ni], acc[mi][ni], 0, 0, 0);
        }
    }

    #pragma unroll
    for (int mi = 0; mi < 2; mi++)
        #pragma unroll
        for (int ni = 0; ni < 4; ni++)
            #pragma unroll
            for (int reg = 0; reg < 4; reg++) {
                int row = m0 + wm * 32 + mi * 16 + quad * 4 + reg;
                int col = n0 + wn * 64 + ni * 16 + lr;
                outf[(size_t)row * N + col] = acc[mi][ni][reg] + bias[col];
            }
}

// ---------------------------------------------------------------------------
// Flash attention v8 (unchanged): 32x32x16, 2-way kv-split,
// register P, double-buffered K/V LDS -> one barrier/iter.
// ---------------------------------------------------------------------------
__global__ __launch_bounds__(512, 4) void attn_kernel(
    const bf16_t* __restrict__ qws, const bf16_t* __restrict__ kws,
    const bf16_t* __restrict__ vtws, bf16_t* __restrict__ ob)
{
    __shared__ __align__(16) bf16_t smem[34048];
    bf16_t* Ks = smem;
    bf16_t* Vs = smem + 16640;

    const int tid  = threadIdx.x;
    const int w    = tid >> 6;
    const int g    = w >> 2;
    const int wg   = w & 3;
    const int lane = tid & 63;
    const int ln31 = lane & 31;
    const int ln5  = lane >> 5;

    const int qb = blockIdx.x;
    const int bh = blockIdx.y;
    const int b  = bh >> 4;
    const int h  = bh & 15;

    const bf16_t* Qh  = qws  + (size_t)bh * SS * HDD;
    const bf16_t* Kh  = kws  + (size_t)bh * SS * HDD;
    const bf16_t* Vth = vtws + (size_t)bh * HDD * SS;

    const int q0w    = qb * 128 + wg * 32;
    const int kvbase = g * 1024;

    bf16x8 aq[4];
    #pragma unroll
    for (int f = 0; f < 4; f++)
        aq[f] = *(const bf16x8*)(Qh + (size_t)(q0w + ln31) * HDD + f * 16 + ln5 * 8);

    const int gtid = tid & 255;
    const int sc = gtid & 7;
    const int sr = gtid >> 3;

    {
        const int ko = g * 520;
        const int vo = g * 4352;
        bf16x8 k0 = *(const bf16x8*)(Kh  + (size_t)(kvbase + sr     ) * HDD + sc * 8);
        bf16x8 k1 = *(const bf16x8*)(Kh  + (size_t)(kvbase + sr + 32) * HDD + sc * 8);
        bf16x8 v0 = *(const bf16x8*)(Vth + (size_t)(sr     ) * SS + kvbase + sc * 8);
        bf16x8 v1 = *(const bf16x8*)(Vth + (size_t)(sr + 32) * SS + kvbase + sc * 8);
        *reinterpret_cast<bf16x8*>(&Ks[(ko + sc * 65 + sr     ) * 8]) = k0;
        *reinterpret_cast<bf16x8*>(&Ks[(ko + sc * 65 + sr + 32) * 8]) = k1;
        bf16_t* vd0 = &Vs[vo + (sr     ) * 68 + sc * 8];
        bf16_t* vd1 = &Vs[vo + (sr + 32) * 68 + sc * 8];
        *reinterpret_cast<bf16x4*>(vd0)     = __builtin_shufflevector(v0, v0, 0,1,2,3);
        *reinterpret_cast<bf16x4*>(vd0 + 4) = __builtin_shufflevector(v0, v0, 4,5,6,7);
        *reinterpret_cast<bf16x4*>(vd1)     = __builtin_shufflevector(v1, v1, 0,1,2,3);
        *reinterpret_cast<bf16x4*>(vd1 + 4) = __builtin_shufflevector(v1, v1, 4,5,6,7);
    }
    __syncthreads();

    float l = 0.f;
    f32x16 o[2];
    #pragma unroll
    for (int nh = 0; nh < 2; nh++)
        #pragma unroll
        for (int r = 0; r < 16; r++) o[nh][r] = 0.f;

    int buf = 0;
    for (int it = 0; it < 16; ++it) {
        const int ko = buf * 1040 + g * 520;
        const int vo = buf * 8704 + g * 4352;

        f32x16 sfr[2];
        #pragma unroll
        for (int ni = 0; ni < 2; ni++) {
            #pragma unroll
            for (int r = 0; r < 16; r++) sfr[ni][r] = 0.f;
            #pragma unroll
            for (int f = 0; f < 4; f++) {
                bf16x8 kb = *reinterpret_cast<const bf16x8*>(
                    &Ks[(ko + (2 * f + ln5) * 65 + ni * 32 + ln31) * 8]);
                sfr[ni] = __builtin_amdgcn_mfma_f32_32x32x16_bf16(kb, aq[f], sfr[ni], 0, 0, 0);
            }
        }

        bf16x8 nk0, nk1, nv0, nv1;
        const bool more = (it + 1 < 16);
        if (more) {
            const int kvn = kvbase + (it + 1) * 64;
            nk0 = *(const bf16x8*)(Kh  + (size_t)(kvn + sr     ) * HDD + sc * 8);
            nk1 = *(const bf16x8*)(Kh  + (size_t)(kvn + sr + 32) * HDD + sc * 8);
            nv0 = *(const bf16x8*)(Vth + (size_t)(sr     ) * SS + kvn + sc * 8);
            nv1 = *(const bf16x8*)(Vth + (size_t)(sr + 32) * SS + kvn + sc * 8);
        }

        float p[2][16];
        #pragma unroll
        for (int ni = 0; ni < 2; ni++)
            #pragma unroll
            for (int r = 0; r < 16; r++) {
                p[ni][r] = __builtin_amdgcn_exp2f(sfr[ni][r]);
                l += p[ni][r];
            }

        bf16x8 ap[4];
        #pragma unroll
        for (int c16 = 0; c16 < 4; c16++)
            #pragma unroll
            for (int j = 0; j < 8; j++)
                ap[c16][j] = (bf16_t)p[c16 >> 1][(c16 & 1) * 8 + j];

        #pragma unroll
        for (int nh = 0; nh < 2; nh++) {
            const bf16_t* vrow = &Vs[vo + (nh * 32 + ln31) * 68];
            #pragma unroll
            for (int c16 = 0; c16 < 4; c16++) {
                bf16x4 lo = *(const bf16x4*)(vrow + c16 * 16 + 4 * ln5);
                bf16x4 hi = *(const bf16x4*)(vrow + c16 * 16 + 8 + 4 * ln5);
                bf16x8 vb = __builtin_shufflevector(lo, hi, 0, 1, 2, 3, 4, 5, 6, 7);
                o[nh] = __builtin_amdgcn_mfma_f32_32x32x16_bf16(ap[c16], vb, o[nh], 0, 0, 0);
            }
        }

        if (more) {
            const int ko1 = (buf ^ 1) * 1040 + g * 520;
            const int vo1 = (buf ^ 1) * 8704 + g * 4352;
            *reinterpret_cast<bf16x8*>(&Ks[(ko1 + sc * 65 + sr     ) * 8]) = nk0;
            *reinterpret_cast<bf16x8*>(&Ks[(ko1 + sc * 65 + sr + 32) * 8]) = nk1;
            bf16_t* vd0 = &Vs[vo1 + (sr     ) * 68 + sc * 8];
            bf16_t* vd1 = &Vs[vo1 + (sr + 32) * 68 + sc * 8];
            *reinterpret_cast<bf16x4*>(vd0)     = __builtin_shufflevector(nv0, nv0, 0,1,2,3);
            *reinterpret_cast<bf16x4*>(vd0 + 4) = __builtin_shufflevector(nv0, nv0, 4,5,6,7);
            *reinterpret_cast<bf16x4*>(vd1)     = __builtin_shufflevector(nv1, nv1, 0,1,2,3);
            *reinterpret_cast<bf16x4*>(vd1 + 4) = __builtin_shufflevector(nv1, nv1, 4,5,6,7);
        }
        __syncthreads();
        buf ^= 1;
    }

    l += __shfl_xor(l, 32, 64);

    __syncthreads();
    float* Of = (float*)smem;
    float* Lf = (float*)(smem + 16384);
    if (ln5 == 0) Lf[g * 128 + wg * 32 + ln31] = l;
    if (g == 1) {
        #pragma unroll
        for (int nh = 0; nh < 2; nh++)
            #pragma unroll
            for (int r = 0; r < 16; r++) {
                const int q = (r & 3) + 8 * (r >> 2) + 4 * ln5;
                Of[(wg * 32 + q) * 64 + nh * 32 + ln31] = o[nh][r];
            }
    }
    __syncthreads();
    if (g == 0) {
        float inv[16];
        #pragma unroll
        for (int r = 0; r < 16; r++) {
            const int q = (r & 3) + 8 * (r >> 2) + 4 * ln5;
            inv[r] = 1.f / (Lf[wg * 32 + q] + Lf[128 + wg * 32 + q]);
        }
        #pragma unroll
        for (int nh = 0; nh < 2; nh++)
            #pragma unroll
            for (int r = 0; r < 16; r++) {
                const int q  = (r & 3) + 8 * (r >> 2) + 4 * ln5;
                const int hd = nh * 32 + ln31;
                float val = (o[nh][r] + Of[(wg * 32 + q) * 64 + hd]) * inv[r];
                ob[((size_t)b * SS + q0w + q) * DD + h * HDD + hd] = (bf16_t)val;
            }
    }
}

// ---------------------------------------------------------------------------
extern "C" void kernel_launch(void* const* d_in, const int* in_sizes, int n_in,
                              void* d_out, int out_size, void* d_ws, size_t ws_size,
                              hipStream_t stream) {
    const float* x     = (const float*)d_in[0];
    const float* Wqkv  = (const float*)d_in[1];
    const float* bqkv  = (const float*)d_in[2];
    const float* Wproj = (const float*)d_in[3];
    const float* bproj = (const float*)d_in[4];
    float* out = (float*)d_out;

    const size_t NEL = (size_t)MM * DD;   // 4194304
    bf16_t* qws    = (bf16_t*)d_ws;
    bf16_t* kws    = qws  + NEL;
    bf16_t* vtws   = kws  + NEL;
    bf16_t* xb     = vtws + NEL;          // aliased: xb then ows
    bf16_t* ows    = xb;
    bf16_t* wqkvt  = xb + NEL;
    bf16_t* wprojt = wqkvt + (size_t)NQKV * DD;

    prep<<<6144, 256, 0, stream>>>(x, Wqkv, Wproj, xb, wqkvt, wprojt);

    gemm_qkv<<<dim3(NQKV / 192, MM / 256), 512, 0, stream>>>(
        xb, wqkvt, bqkv, qws, kws, vtws);

    attn_kernel<<<dim3(SS / 128, BB * HH), 512, 0, stream>>>(qws, kws, vtws, ows);

    gemm_bt64<<<dim3(DD / 128, MM / 64), 256, 0, stream>>>(
        ows, wprojt, bproj, out, DD, DD);
}

// Round 4
// 179.395 us; speedup vs baseline: 1.0733x; 1.0020x over previous
//
#include <hip/hip_runtime.h>
#include <hip/hip_bf16.h>

// Problem constants
#define BB 2
#define SS 2048
#define DD 1024
#define HH 16
#define HDD 64
#define MM (BB*SS)          // 4096
#define NQKV (3*DD)         // 3072
#define SCALE 0.125f        // HD^-0.5
#define QPRESCALE 0.18033688f   // SCALE * log2(e), folded into Q at GEMM epilogue

typedef __bf16 bf16_t;
typedef bf16_t bf16x4 __attribute__((ext_vector_type(4)));
typedef bf16_t bf16x8 __attribute__((ext_vector_type(8)));
typedef float f32x4 __attribute__((ext_vector_type(4)));
typedef float f32x16 __attribute__((ext_vector_type(16)));

// ---------------------------------------------------------------------------
// global -> LDS direct DMA, 16B per lane.
// ---------------------------------------------------------------------------
__device__ __forceinline__ void gl_lds16(const bf16_t* g, bf16_t* l) {
    __builtin_amdgcn_global_load_lds(
        (const __attribute__((address_space(1))) unsigned int*)(uintptr_t)g,
        (__attribute__((address_space(3))) unsigned int*)(uintptr_t)l,
        16, 0, 0);
}

__device__ __forceinline__ f32x4 MF(bf16x8 a, bf16x8 b, f32x4 c) {
    return __builtin_amdgcn_mfma_f32_16x16x32_bf16(a, b, c, 0, 0, 0);
}

// ---------------------------------------------------------------------------
// Fused prep kernel (one launch):
//   blocks [0,2048): convert x f32 -> bf16 (8 elems/thread)
//   blocks [2048,5120): transpose Wqkv -> wqkvt [3072][1024] bf16 (96x32 tiles)
//   blocks [5120,6144): transpose Wproj -> wprojt [1024][1024] bf16 (32x32 tiles)
// ---------------------------------------------------------------------------
__global__ __launch_bounds__(256) void prep(
    const float* __restrict__ x, const float* __restrict__ Wqkv,
    const float* __restrict__ Wproj, bf16_t* __restrict__ xb,
    bf16_t* __restrict__ wqkvt, bf16_t* __restrict__ wprojt)
{
    const int bx = blockIdx.x;
    if (bx < 2048) {
        int i = (bx * 256 + threadIdx.x) * 8;
        float4 a = *(const float4*)(x + i);
        float4 b = *(const float4*)(x + i + 4);
        bf16x8 v;
        v[0]=(bf16_t)a.x; v[1]=(bf16_t)a.y; v[2]=(bf16_t)a.z; v[3]=(bf16_t)a.w;
        v[4]=(bf16_t)b.x; v[5]=(bf16_t)b.y; v[6]=(bf16_t)b.z; v[7]=(bf16_t)b.w;
        *reinterpret_cast<bf16x8*>(xb + i) = v;
        return;
    }
    __shared__ float tile[32][33];
    const float* src; bf16_t* dst; int C, bxl, byl;
    if (bx < 5120) {
        int t = bx - 2048;
        byl = t / 96; bxl = t - byl * 96;   // 96 not pow2 -> real division
        src = Wqkv;  dst = wqkvt;  C = NQKV;
    } else {
        int t = bx - 5120;
        byl = t >> 5; bxl = t & 31;
        src = Wproj; dst = wprojt; C = DD;
    }
    const int R = DD;
    const int tx = threadIdx.x & 31, ty = threadIdx.x >> 5;
    const int r0 = byl * 32, c0 = bxl * 32;
    #pragma unroll
    for (int i = 0; i < 32; i += 8)
        tile[ty + i][tx] = src[(size_t)(r0 + ty + i) * C + c0 + tx];
    __syncthreads();
    #pragma unroll
    for (int i = 0; i < 32; i += 8)
        dst[(size_t)(c0 + ty + i) * R + r0 + tx] = (bf16_t)tile[tx][ty + i];
}

// ---------------------------------------------------------------------------
// QKV GEMM (R3 resubmit; R3 bench was an infra failure, kernel re-audited):
// BM=256, BN=192, BK=32, 512 threads = 8 waves (2M x 4N),
// grid 16x16 = 256 blocks = 1/CU, XCD-swizzled.
// Counted-vmcnt 3-buffer pipeline (m218's +38-73% lever):
//   tile t computes buf[t%3], issues stage(t+2 -> buf[(t+2)%3]);
//   tile end: vmcnt(4) -- t+2's 4 loads stay IN FLIGHT across the barrier,
//   t+1's loads (issued a tile earlier) have ~2 tiles of cover.
//   ONE s_barrier per tile; no mid-tile barrier (waves drift -> LDS bursts
//   stagger against MFMA; setprio keeps MFMA waves fed).
// BK=32 rows (64B) make frag reads conflict-free with NO swizzle:
//   each 4-bank group serves exactly 8 lanes of a b128 wave read.
// Audit notes: all s_barriers block-uniform; stage dests wave-uniform+lane*16;
// buffer rotation & vmcnt counts verified over the unrolled tail; bounds OK.
// ---------------------------------------------------------------------------
__global__ __launch_bounds__(512, 2) void gemm_qkv(
    const bf16_t* __restrict__ A, const bf16_t* __restrict__ Bt,
    const float* __restrict__ bias,
    bf16_t* __restrict__ qw, bf16_t* __restrict__ kw, bf16_t* __restrict__ vtw)
{
    constexpr int K  = DD;          // 1024
    constexpr int BM = 256, BN = 192, BK = 32;
    constexpr int NT = K / BK;      // 32

    // 3 A-buffers (8192 el) + 3 B-buffers (6144 el) = 43008 el;
    // epilogue V-transpose needs up to 191*260+256 = 49916 el.
    __shared__ __align__(16) bf16_t smem[50176];   // 100352 B -> 1 block/CU
    bf16_t* const Ab[3] = { smem, smem + 8192, smem + 16384 };
    bf16_t* const Bb[3] = { smem + 24576, smem + 30720, smem + 36864 };

    const int tid  = threadIdx.x;
    const int w    = tid >> 6;
    const int lane = tid & 63;
    const int lr   = lane & 15;
    const int quad = lane >> 4;
    const int wm   = w >> 2;        // 0..1 -> rows wm*128..+127
    const int wn   = w & 3;         // 0..3 -> cols wn*48..+47

    // XCD-aware bijective swizzle (256 blocks, 8 XCDs): XCD k gets 2 M-panels.
    const int flat = blockIdx.y * 16 + blockIdx.x;
    const int swz  = (flat & 7) * 32 + (flat >> 3);
    const int m0   = (swz >> 4) * BM;
    const int n0   = (swz & 15) * BN;

    f32x4 acc[8][3];
    #pragma unroll
    for (int mi = 0; mi < 8; mi++)
        #pragma unroll
        for (int ni = 0; ni < 3; ni++)
            acc[mi][ni] = (f32x4){0.f, 0.f, 0.f, 0.f};

    // staging: A = 1024 chunks of 16B (256 rows x 4), 2/thread;
    //          B = 768 chunks (192 rows x 4), 2/thread (256..511 duplicated,
    //          benign double-DMA of identical data) -> uniform 4 loads/thread.
    const int ca0 = tid,        ca1 = tid + 512;
    const int cb0 = tid,        cb1 = tid + 256;
    const bf16_t* aG0 = A  + (size_t)(m0 + (ca0 >> 2)) * K + (ca0 & 3) * 8;
    const bf16_t* aG1 = A  + (size_t)(m0 + (ca1 >> 2)) * K + (ca1 & 3) * 8;
    const bf16_t* bG0 = Bt + (size_t)(n0 + (cb0 >> 2)) * K + (cb0 & 3) * 8;
    const bf16_t* bG1 = Bt + (size_t)(n0 + (cb1 >> 2)) * K + (cb1 & 3) * 8;

    auto stage = [&](int kt, bf16_t* Ad, bf16_t* Bd) {
        const int ko = kt * BK;
        gl_lds16(aG0 + ko, Ad + ca0 * 8);
        gl_lds16(aG1 + ko, Ad + ca1 * 8);
        gl_lds16(bG0 + ko, Bd + cb0 * 8);
        gl_lds16(bG1 + ko, Bd + cb1 * 8);
    };

    // prologue: fill buf0, buf1; wait buf0 (buf1's 4 stay outstanding)
    stage(0, Ab[0], Bb[0]);
    stage(1, Ab[1], Bb[1]);
    asm volatile("s_waitcnt vmcnt(4)" ::: "memory");
    __builtin_amdgcn_s_barrier();
    __builtin_amdgcn_sched_barrier(0);

    const int aOff = (wm * 128 + lr) * BK + quad * 8;
    const int bOff = (wn * 48  + lr) * BK + quad * 8;

    auto tileStep = [&](int t, const bf16_t* Ac, const bf16_t* Bc,
                        bf16_t* An, bf16_t* Bn) {
        bf16x8 af[8], bk[3];
        #pragma unroll
        for (int mi = 0; mi < 8; mi++)
            af[mi] = *(const bf16x8*)(Ac + aOff + mi * 16 * BK);
        #pragma unroll
        for (int ni = 0; ni < 3; ni++)
            bk[ni] = *(const bf16x8*)(Bc + bOff + ni * 16 * BK);
        if (t < NT - 2) stage(t + 2, An, Bn);
        __builtin_amdgcn_sched_barrier(0);
        __builtin_amdgcn_s_setprio(1);
        #pragma unroll
        for (int mi = 0; mi < 8; mi++)
            #pragma unroll
            for (int ni = 0; ni < 3; ni++)
                acc[mi][ni] = MF(af[mi], bk[ni], acc[mi][ni]);
        __builtin_amdgcn_s_setprio(0);
        __builtin_amdgcn_sched_barrier(0);
        if (t < NT - 2)       asm volatile("s_waitcnt vmcnt(4)" ::: "memory");
        else if (t == NT - 2) asm volatile("s_waitcnt vmcnt(0)" ::: "memory");
        __builtin_amdgcn_s_barrier();
        __builtin_amdgcn_sched_barrier(0);
    };

    #pragma unroll 1
    for (int tt = 0; tt < NT - 2; tt += 3) {
        tileStep(tt,     Ab[0], Bb[0], Ab[2], Bb[2]);
        tileStep(tt + 1, Ab[1], Bb[1], Ab[0], Bb[0]);
        tileStep(tt + 2, Ab[2], Bb[2], Ab[1], Bb[1]);
    }
    tileStep(NT - 2, Ab[0], Bb[0], nullptr, nullptr);   // t=30: vmcnt(0)
    tileStep(NT - 1, Ab[1], Bb[1], nullptr, nullptr);   // t=31

    // ---- epilogue ----------------------------------------------------------
    __builtin_amdgcn_s_barrier();   // all LDS reads done before smem reuse

    const int colBase = n0 + wn * 48;
    const int vbase   = (n0 < 2048) ? 2048 : n0;   // first V column this block
    // pass 1: direct q/k stores; V accs -> LDS [lcol][260] (row-padded)
    #pragma unroll
    for (int mi = 0; mi < 8; mi++) {
        const int rl0 = wm * 128 + mi * 16 + quad * 4;
        #pragma unroll
        for (int ni = 0; ni < 3; ni++) {
            const int col = colBase + ni * 16 + lr;
            const float bcol = bias[col];
            const int which = col >> 10;
            const int d = col & 1023;
            const int h = d >> 6, hd = d & 63;
            if (which == 0) {
                #pragma unroll
                for (int reg = 0; reg < 4; reg++) {
                    const int row = m0 + rl0 + reg;
                    const int b = row >> 11, s = row & 2047;
                    qw[(((size_t)(b * HH + h)) * SS + s) * HDD + hd] =
                        (bf16_t)((acc[mi][ni][reg] + bcol) * QPRESCALE);
                }
            } else if (which == 1) {
                #pragma unroll
                for (int reg = 0; reg < 4; reg++) {
                    const int row = m0 + rl0 + reg;
                    const int b = row >> 11, s = row & 2047;
                    kw[(((size_t)(b * HH + h)) * SS + s) * HDD + hd] =
                        (bf16_t)(acc[mi][ni][reg] + bcol);
                }
            } else {
                bf16x4 pk;
                #pragma unroll
                for (int reg = 0; reg < 4; reg++)
                    pk[reg] = (bf16_t)(acc[mi][ni][reg] + bcol);
                const int lc = col - vbase;
                *reinterpret_cast<bf16x4*>(&smem[lc * 260 + rl0]) = pk;
            }
        }
    }
    // pass 2: coalesced V^T stores (16B along S)
    const int nv = n0 + BN - 2048;
    if (nv > 0) {
        __builtin_amdgcn_s_barrier();
        const int nvc = nv < BN ? nv : BN;
        const int lcb = tid >> 5;            // 0..15
        const int rl  = (tid & 31) * 8;      // 0..248
        const int b   = m0 >> 11;
        const int s   = (m0 & 2047) + rl;
        for (int j = 0; j < nvc / 16; j++) {
            const int lc = j * 16 + lcb;
            bf16x8 vv = *reinterpret_cast<const bf16x8*>(&smem[lc * 260 + rl]);
            const int col = vbase + lc;
            const int d = col & 1023;
            const int h = d >> 6, hd = d & 63;
            *reinterpret_cast<bf16x8*>(
                vtw + (((size_t)(b * HH + h)) * HDD + hd) * SS + s) = vv;
        }
    }
}

// ---------------------------------------------------------------------------
// BM=64 proj GEMM, BK=64 (grid 512 = 2/CU). Unchanged this round.
// ---------------------------------------------------------------------------
__global__ __launch_bounds__(256) void gemm_bt64(
    const bf16_t* __restrict__ A, const bf16_t* __restrict__ Bt,
    const float* __restrict__ bias, float* __restrict__ outf, int N, int K)
{
    __shared__ __align__(16) bf16_t As[2][64 * 32];
    __shared__ __align__(16) bf16_t Bs[2][128 * 32];

    const int tid  = threadIdx.x;
    const int w    = tid >> 6;
    const int lane = tid & 63;
    const int lr   = lane & 15;
    const int quad = lane >> 4;
    const int m0   = blockIdx.y * 64;
    const int n0   = blockIdx.x * 128;
    const int wm   = w >> 1;
    const int wn   = w & 1;

    f32x4 acc[2][4];
    #pragma unroll
    for (int i = 0; i < 2; i++)
        #pragma unroll
        for (int j = 0; j < 4; j++) acc[i][j] = (f32x4){0.f, 0.f, 0.f, 0.f};

    const int stgRow = lane >> 2;
    const int stgCol = (lane & 3) * 8;
    const bf16_t* aPtr = A  + (size_t)(m0 + w * 16 + stgRow) * K + stgCol;
    const bf16_t* bPtr = Bt + (size_t)(n0 + w * 32 + stgRow) * K + stgCol;
    const size_t rowSkip = (size_t)16 * K;

    for (int ks = 0; ks < K; ks += 64) {
        __syncthreads();
        #pragma unroll
        for (int s = 0; s < 2; s++) {
            const int ko = ks + s * 32;
            gl_lds16(aPtr + ko,           &As[s][w * 512]);
            gl_lds16(bPtr + ko,           &Bs[s][w * 1024]);
            gl_lds16(bPtr + rowSkip + ko, &Bs[s][w * 1024 + 512]);
        }
        __syncthreads();

        #pragma unroll
        for (int s = 0; s < 2; s++) {
            bf16x8 af[2], bf[4];
            #pragma unroll
            for (int mi = 0; mi < 2; mi++)
                af[mi] = *reinterpret_cast<const bf16x8*>(&As[s][(wm * 32 + mi * 16 + lr) * 32 + quad * 8]);
            #pragma unroll
            for (int ni = 0; ni < 4; ni++)
                bf[ni] = *reinterpret_cast<const bf16x8*>(&Bs[s][(wn * 64 + ni * 16 + lr) * 32 + quad * 8]);
            #pragma unroll
            for (int mi = 0; mi < 2; mi++)
                #pragma unroll
                for (int ni = 0; ni < 4; ni++)
                    acc[mi][ni] = __builtin_amdgcn_mfma_f32_16x16x32_bf16(af[mi], bf[ni], acc[mi][ni], 0, 0, 0);
        }
    }

    #pragma unroll
    for (int mi = 0; mi < 2; mi++)
        #pragma unroll
        for (int ni = 0; ni < 4; ni++)
            #pragma unroll
            for (int reg = 0; reg < 4; reg++) {
                int row = m0 + wm * 32 + mi * 16 + quad * 4 + reg;
                int col = n0 + wn * 64 + ni * 16 + lr;
                outf[(size_t)row * N + col] = acc[mi][ni][reg] + bias[col];
            }
}

// ---------------------------------------------------------------------------
// Flash attention v8 (unchanged): 32x32x16, 2-way kv-split,
// register P, double-buffered K/V LDS -> one barrier/iter.
// ---------------------------------------------------------------------------
__global__ __launch_bounds__(512, 4) void attn_kernel(
    const bf16_t* __restrict__ qws, const bf16_t* __restrict__ kws,
    const bf16_t* __restrict__ vtws, bf16_t* __restrict__ ob)
{
    __shared__ __align__(16) bf16_t smem[34048];
    bf16_t* Ks = smem;
    bf16_t* Vs = smem + 16640;

    const int tid  = threadIdx.x;
    const int w    = tid >> 6;
    const int g    = w >> 2;
    const int wg   = w & 3;
    const int lane = tid & 63;
    const int ln31 = lane & 31;
    const int ln5  = lane >> 5;

    const int qb = blockIdx.x;
    const int bh = blockIdx.y;
    const int b  = bh >> 4;
    const int h  = bh & 15;

    const bf16_t* Qh  = qws  + (size_t)bh * SS * HDD;
    const bf16_t* Kh  = kws  + (size_t)bh * SS * HDD;
    const bf16_t* Vth = vtws + (size_t)bh * HDD * SS;

    const int q0w    = qb * 128 + wg * 32;
    const int kvbase = g * 1024;

    bf16x8 aq[4];
    #pragma unroll
    for (int f = 0; f < 4; f++)
        aq[f] = *(const bf16x8*)(Qh + (size_t)(q0w + ln31) * HDD + f * 16 + ln5 * 8);

    const int gtid = tid & 255;
    const int sc = gtid & 7;
    const int sr = gtid >> 3;

    {
        const int ko = g * 520;
        const int vo = g * 4352;
        bf16x8 k0 = *(const bf16x8*)(Kh  + (size_t)(kvbase + sr     ) * HDD + sc * 8);
        bf16x8 k1 = *(const bf16x8*)(Kh  + (size_t)(kvbase + sr + 32) * HDD + sc * 8);
        bf16x8 v0 = *(const bf16x8*)(Vth + (size_t)(sr     ) * SS + kvbase + sc * 8);
        bf16x8 v1 = *(const bf16x8*)(Vth + (size_t)(sr + 32) * SS + kvbase + sc * 8);
        *reinterpret_cast<bf16x8*>(&Ks[(ko + sc * 65 + sr     ) * 8]) = k0;
        *reinterpret_cast<bf16x8*>(&Ks[(ko + sc * 65 + sr + 32) * 8]) = k1;
        bf16_t* vd0 = &Vs[vo + (sr     ) * 68 + sc * 8];
        bf16_t* vd1 = &Vs[vo + (sr + 32) * 68 + sc * 8];
        *reinterpret_cast<bf16x4*>(vd0)     = __builtin_shufflevector(v0, v0, 0,1,2,3);
        *reinterpret_cast<bf16x4*>(vd0 + 4) = __builtin_shufflevector(v0, v0, 4,5,6,7);
        *reinterpret_cast<bf16x4*>(vd1)     = __builtin_shufflevector(v1, v1, 0,1,2,3);
        *reinterpret_cast<bf16x4*>(vd1 + 4) = __builtin_shufflevector(v1, v1, 4,5,6,7);
    }
    __syncthreads();

    float l = 0.f;
    f32x16 o[2];
    #pragma unroll
    for (int nh = 0; nh < 2; nh++)
        #pragma unroll
        for (int r = 0; r < 16; r++) o[nh][r] = 0.f;

    int buf = 0;
    for (int it = 0; it < 16; ++it) {
        const int ko = buf * 1040 + g * 520;
        const int vo = buf * 8704 + g * 4352;

        f32x16 sfr[2];
        #pragma unroll
        for (int ni = 0; ni < 2; ni++) {
            #pragma unroll
            for (int r = 0; r < 16; r++) sfr[ni][r] = 0.f;
            #pragma unroll
            for (int f = 0; f < 4; f++) {
                bf16x8 kb = *reinterpret_cast<const bf16x8*>(
                    &Ks[(ko + (2 * f + ln5) * 65 + ni * 32 + ln31) * 8]);
                sfr[ni] = __builtin_amdgcn_mfma_f32_32x32x16_bf16(kb, aq[f], sfr[ni], 0, 0, 0);
            }
        }

        bf16x8 nk0, nk1, nv0, nv1;
        const bool more = (it + 1 < 16);
        if (more) {
            const int kvn = kvbase + (it + 1) * 64;
            nk0 = *(const bf16x8*)(Kh  + (size_t)(kvn + sr     ) * HDD + sc * 8);
            nk1 = *(const bf16x8*)(Kh  + (size_t)(kvn + sr + 32) * HDD + sc * 8);
            nv0 = *(const bf16x8*)(Vth + (size_t)(sr     ) * SS + kvn + sc * 8);
            nv1 = *(const bf16x8*)(Vth + (size_t)(sr + 32) * SS + kvn + sc * 8);
        }

        float p[2][16];
        #pragma unroll
        for (int ni = 0; ni < 2; ni++)
            #pragma unroll
            for (int r = 0; r < 16; r++) {
                p[ni][r] = __builtin_amdgcn_exp2f(sfr[ni][r]);
                l += p[ni][r];
            }

        bf16x8 ap[4];
        #pragma unroll
        for (int c16 = 0; c16 < 4; c16++)
            #pragma unroll
            for (int j = 0; j < 8; j++)
                ap[c16][j] = (bf16_t)p[c16 >> 1][(c16 & 1) * 8 + j];

        #pragma unroll
        for (int nh = 0; nh < 2; nh++) {
            const bf16_t* vrow = &Vs[vo + (nh * 32 + ln31) * 68];
            #pragma unroll
            for (int c16 = 0; c16 < 4; c16++) {
                bf16x4 lo = *(const bf16x4*)(vrow + c16 * 16 + 4 * ln5);
                bf16x4 hi = *(const bf16x4*)(vrow + c16 * 16 + 8 + 4 * ln5);
                bf16x8 vb = __builtin_shufflevector(lo, hi, 0, 1, 2, 3, 4, 5, 6, 7);
                o[nh] = __builtin_amdgcn_mfma_f32_32x32x16_bf16(ap[c16], vb, o[nh], 0, 0, 0);
            }
        }

        if (more) {
            const int ko1 = (buf ^ 1) * 1040 + g * 520;
            const int vo1 = (buf ^ 1) * 8704 + g * 4352;
            *reinterpret_cast<bf16x8*>(&Ks[(ko1 + sc * 65 + sr     ) * 8]) = nk0;
            *reinterpret_cast<bf16x8*>(&Ks[(ko1 + sc * 65 + sr + 32) * 8]) = nk1;
            bf16_t* vd0 = &Vs[vo1 + (sr     ) * 68 + sc * 8];
            bf16_t* vd1 = &Vs[vo1 + (sr + 32) * 68 + sc * 8];
            *reinterpret_cast<bf16x4*>(vd0)     = __builtin_shufflevector(nv0, nv0, 0,1,2,3);
            *reinterpret_cast<bf16x4*>(vd0 + 4) = __builtin_shufflevector(nv0, nv0, 4,5,6,7);
            *reinterpret_cast<bf16x4*>(vd1)     = __builtin_shufflevector(nv1, nv1, 0,1,2,3);
            *reinterpret_cast<bf16x4*>(vd1 + 4) = __builtin_shufflevector(nv1, nv1, 4,5,6,7);
        }
        __syncthreads();
        buf ^= 1;
    }

    l += __shfl_xor(l, 32, 64);

    __syncthreads();
    float* Of = (float*)smem;
    float* Lf = (float*)(smem + 16384);
    if (ln5 == 0) Lf[g * 128 + wg * 32 + ln31] = l;
    if (g == 1) {
        #pragma unroll
        for (int nh = 0; nh < 2; nh++)
            #pragma unroll
            for (int r = 0; r < 16; r++) {
                const int q = (r & 3) + 8 * (r >> 2) + 4 * ln5;
                Of[(wg * 32 + q) * 64 + nh * 32 + ln31] = o[nh][r];
            }
    }
    __syncthreads();
    if (g == 0) {
        float inv[16];
        #pragma unroll
        for (int r = 0; r < 16; r++) {
            const int q = (r & 3) + 8 * (r >> 2) + 4 * ln5;
            inv[r] = 1.f / (Lf[wg * 32 + q] + Lf[128 + wg * 32 + q]);
        }
        #pragma unroll
        for (int nh = 0; nh < 2; nh++)
            #pragma unroll
            for (int r = 0; r < 16; r++) {
                const int q  = (r & 3) + 8 * (r >> 2) + 4 * ln5;
                const int hd = nh * 32 + ln31;
                float val = (o[nh][r] + Of[(wg * 32 + q) * 64 + hd]) * inv[r];
                ob[((size_t)b * SS + q0w + q) * DD + h * HDD + hd] = (bf16_t)val;
            }
    }
}

// ---------------------------------------------------------------------------
extern "C" void kernel_launch(void* const* d_in, const int* in_sizes, int n_in,
                              void* d_out, int out_size, void* d_ws, size_t ws_size,
                              hipStream_t stream) {
    const float* x     = (const float*)d_in[0];
    const float* Wqkv  = (const float*)d_in[1];
    const float* bqkv  = (const float*)d_in[2];
    const float* Wproj = (const float*)d_in[3];
    const float* bproj = (const float*)d_in[4];
    float* out = (float*)d_out;

    const size_t NEL = (size_t)MM * DD;   // 4194304
    bf16_t* qws    = (bf16_t*)d_ws;
    bf16_t* kws    = qws  + NEL;
    bf16_t* vtws   = kws  + NEL;
    bf16_t* xb     = vtws + NEL;          // aliased: xb then ows
    bf16_t* ows    = xb;
    bf16_t* wqkvt  = xb + NEL;
    bf16_t* wprojt = wqkvt + (size_t)NQKV * DD;

    prep<<<6144, 256, 0, stream>>>(x, Wqkv, Wproj, xb, wqkvt, wprojt);

    gemm_qkv<<<dim3(NQKV / 192, MM / 256), 512, 0, stream>>>(
        xb, wqkvt, bqkv, qws, kws, vtws);

    attn_kernel<<<dim3(SS / 128, BB * HH), 512, 0, stream>>>(qws, kws, vtws, ows);

    gemm_bt64<<<dim3(DD / 128, MM / 64), 256, 0, stream>>>(
        ows, wprojt, bproj, out, DD, DD);
}

// Round 5
// 172.359 us; speedup vs baseline: 1.1171x; 1.0408x over previous
//
#include <hip/hip_runtime.h>
#include <hip/hip_bf16.h>

// Problem constants
#define BB 2
#define SS 2048
#define DD 1024
#define HH 16
#define HDD 64
#define MM (BB*SS)          // 4096
#define NQKV (3*DD)         // 3072
#define SCALE 0.125f        // HD^-0.5
#define QPRESCALE 0.18033688f   // SCALE * log2(e), folded into Q at GEMM epilogue

typedef __bf16 bf16_t;
typedef bf16_t bf16x4 __attribute__((ext_vector_type(4)));
typedef bf16_t bf16x8 __attribute__((ext_vector_type(8)));
typedef float f32x4 __attribute__((ext_vector_type(4)));
typedef float f32x16 __attribute__((ext_vector_type(16)));

// ---------------------------------------------------------------------------
// global -> LDS direct DMA, 16B per lane.
// ---------------------------------------------------------------------------
__device__ __forceinline__ void gl_lds16(const bf16_t* g, bf16_t* l) {
    __builtin_amdgcn_global_load_lds(
        (const __attribute__((address_space(1))) unsigned int*)(uintptr_t)g,
        (__attribute__((address_space(3))) unsigned int*)(uintptr_t)l,
        16, 0, 0);
}

__device__ __forceinline__ f32x4 MF(bf16x8 a, bf16x8 b, f32x4 c) {
    return __builtin_amdgcn_mfma_f32_16x16x32_bf16(a, b, c, 0, 0, 0);
}

// ---------------------------------------------------------------------------
// Fused prep kernel (one launch):
//   blocks [0,2048): convert x f32 -> bf16 (8 elems/thread)
//   blocks [2048,5120): transpose Wqkv -> wqkvt [3072][1024] bf16 (96x32 tiles)
//   blocks [5120,6144): transpose Wproj -> wprojt [1024][1024] bf16 (32x32 tiles)
// ---------------------------------------------------------------------------
__global__ __launch_bounds__(256) void prep(
    const float* __restrict__ x, const float* __restrict__ Wqkv,
    const float* __restrict__ Wproj, bf16_t* __restrict__ xb,
    bf16_t* __restrict__ wqkvt, bf16_t* __restrict__ wprojt)
{
    const int bx = blockIdx.x;
    if (bx < 2048) {
        int i = (bx * 256 + threadIdx.x) * 8;
        float4 a = *(const float4*)(x + i);
        float4 b = *(const float4*)(x + i + 4);
        bf16x8 v;
        v[0]=(bf16_t)a.x; v[1]=(bf16_t)a.y; v[2]=(bf16_t)a.z; v[3]=(bf16_t)a.w;
        v[4]=(bf16_t)b.x; v[5]=(bf16_t)b.y; v[6]=(bf16_t)b.z; v[7]=(bf16_t)b.w;
        *reinterpret_cast<bf16x8*>(xb + i) = v;
        return;
    }
    __shared__ float tile[32][33];
    const float* src; bf16_t* dst; int C, bxl, byl;
    if (bx < 5120) {
        int t = bx - 2048;
        byl = t / 96; bxl = t - byl * 96;   // 96 not pow2 -> real division
        src = Wqkv;  dst = wqkvt;  C = NQKV;
    } else {
        int t = bx - 5120;
        byl = t >> 5; bxl = t & 31;
        src = Wproj; dst = wprojt; C = DD;
    }
    const int R = DD;
    const int tx = threadIdx.x & 31, ty = threadIdx.x >> 5;
    const int r0 = byl * 32, c0 = bxl * 32;
    #pragma unroll
    for (int i = 0; i < 32; i += 8)
        tile[ty + i][tx] = src[(size_t)(r0 + ty + i) * C + c0 + tx];
    __syncthreads();
    #pragma unroll
    for (int i = 0; i < 32; i += 8)
        dst[(size_t)(c0 + ty + i) * R + r0 + tx] = (bf16_t)tile[tx][ty + i];
}

// ---------------------------------------------------------------------------
// QKV GEMM (unchanged from R4, verified): BM=256, BN=192, BK=32,
// 512 threads = 8 waves, 256 blocks = 1/CU, XCD-swizzled,
// counted-vmcnt 3-buffer pipeline, one s_barrier/tile.
// ---------------------------------------------------------------------------
__global__ __launch_bounds__(512, 2) void gemm_qkv(
    const bf16_t* __restrict__ A, const bf16_t* __restrict__ Bt,
    const float* __restrict__ bias,
    bf16_t* __restrict__ qw, bf16_t* __restrict__ kw, bf16_t* __restrict__ vtw)
{
    constexpr int K  = DD;          // 1024
    constexpr int BM = 256, BN = 192, BK = 32;
    constexpr int NT = K / BK;      // 32

    __shared__ __align__(16) bf16_t smem[50176];   // 100352 B -> 1 block/CU
    bf16_t* const Ab[3] = { smem, smem + 8192, smem + 16384 };
    bf16_t* const Bb[3] = { smem + 24576, smem + 30720, smem + 36864 };

    const int tid  = threadIdx.x;
    const int w    = tid >> 6;
    const int lane = tid & 63;
    const int lr   = lane & 15;
    const int quad = lane >> 4;
    const int wm   = w >> 2;        // 0..1 -> rows wm*128..+127
    const int wn   = w & 3;         // 0..3 -> cols wn*48..+47

    // XCD-aware bijective swizzle (256 blocks, 8 XCDs): XCD k gets 2 M-panels.
    const int flat = blockIdx.y * 16 + blockIdx.x;
    const int swz  = (flat & 7) * 32 + (flat >> 3);
    const int m0   = (swz >> 4) * BM;
    const int n0   = (swz & 15) * BN;

    f32x4 acc[8][3];
    #pragma unroll
    for (int mi = 0; mi < 8; mi++)
        #pragma unroll
        for (int ni = 0; ni < 3; ni++)
            acc[mi][ni] = (f32x4){0.f, 0.f, 0.f, 0.f};

    const int ca0 = tid,        ca1 = tid + 512;
    const int cb0 = tid,        cb1 = tid + 256;
    const bf16_t* aG0 = A  + (size_t)(m0 + (ca0 >> 2)) * K + (ca0 & 3) * 8;
    const bf16_t* aG1 = A  + (size_t)(m0 + (ca1 >> 2)) * K + (ca1 & 3) * 8;
    const bf16_t* bG0 = Bt + (size_t)(n0 + (cb0 >> 2)) * K + (cb0 & 3) * 8;
    const bf16_t* bG1 = Bt + (size_t)(n0 + (cb1 >> 2)) * K + (cb1 & 3) * 8;

    auto stage = [&](int kt, bf16_t* Ad, bf16_t* Bd) {
        const int ko = kt * BK;
        gl_lds16(aG0 + ko, Ad + ca0 * 8);
        gl_lds16(aG1 + ko, Ad + ca1 * 8);
        gl_lds16(bG0 + ko, Bd + cb0 * 8);
        gl_lds16(bG1 + ko, Bd + cb1 * 8);
    };

    stage(0, Ab[0], Bb[0]);
    stage(1, Ab[1], Bb[1]);
    asm volatile("s_waitcnt vmcnt(4)" ::: "memory");
    __builtin_amdgcn_s_barrier();
    __builtin_amdgcn_sched_barrier(0);

    const int aOff = (wm * 128 + lr) * BK + quad * 8;
    const int bOff = (wn * 48  + lr) * BK + quad * 8;

    auto tileStep = [&](int t, const bf16_t* Ac, const bf16_t* Bc,
                        bf16_t* An, bf16_t* Bn) {
        bf16x8 af[8], bk[3];
        #pragma unroll
        for (int mi = 0; mi < 8; mi++)
            af[mi] = *(const bf16x8*)(Ac + aOff + mi * 16 * BK);
        #pragma unroll
        for (int ni = 0; ni < 3; ni++)
            bk[ni] = *(const bf16x8*)(Bc + bOff + ni * 16 * BK);
        if (t < NT - 2) stage(t + 2, An, Bn);
        __builtin_amdgcn_sched_barrier(0);
        __builtin_amdgcn_s_setprio(1);
        #pragma unroll
        for (int mi = 0; mi < 8; mi++)
            #pragma unroll
            for (int ni = 0; ni < 3; ni++)
                acc[mi][ni] = MF(af[mi], bk[ni], acc[mi][ni]);
        __builtin_amdgcn_s_setprio(0);
        __builtin_amdgcn_sched_barrier(0);
        if (t < NT - 2)       asm volatile("s_waitcnt vmcnt(4)" ::: "memory");
        else if (t == NT - 2) asm volatile("s_waitcnt vmcnt(0)" ::: "memory");
        __builtin_amdgcn_s_barrier();
        __builtin_amdgcn_sched_barrier(0);
    };

    #pragma unroll 1
    for (int tt = 0; tt < NT - 2; tt += 3) {
        tileStep(tt,     Ab[0], Bb[0], Ab[2], Bb[2]);
        tileStep(tt + 1, Ab[1], Bb[1], Ab[0], Bb[0]);
        tileStep(tt + 2, Ab[2], Bb[2], Ab[1], Bb[1]);
    }
    tileStep(NT - 2, Ab[0], Bb[0], nullptr, nullptr);   // t=30: vmcnt(0)
    tileStep(NT - 1, Ab[1], Bb[1], nullptr, nullptr);   // t=31

    __builtin_amdgcn_s_barrier();   // all LDS reads done before smem reuse

    const int colBase = n0 + wn * 48;
    const int vbase   = (n0 < 2048) ? 2048 : n0;   // first V column this block
    #pragma unroll
    for (int mi = 0; mi < 8; mi++) {
        const int rl0 = wm * 128 + mi * 16 + quad * 4;
        #pragma unroll
        for (int ni = 0; ni < 3; ni++) {
            const int col = colBase + ni * 16 + lr;
            const float bcol = bias[col];
            const int which = col >> 10;
            const int d = col & 1023;
            const int h = d >> 6, hd = d & 63;
            if (which == 0) {
                #pragma unroll
                for (int reg = 0; reg < 4; reg++) {
                    const int row = m0 + rl0 + reg;
                    const int b = row >> 11, s = row & 2047;
                    qw[(((size_t)(b * HH + h)) * SS + s) * HDD + hd] =
                        (bf16_t)((acc[mi][ni][reg] + bcol) * QPRESCALE);
                }
            } else if (which == 1) {
                #pragma unroll
                for (int reg = 0; reg < 4; reg++) {
                    const int row = m0 + rl0 + reg;
                    const int b = row >> 11, s = row & 2047;
                    kw[(((size_t)(b * HH + h)) * SS + s) * HDD + hd] =
                        (bf16_t)(acc[mi][ni][reg] + bcol);
                }
            } else {
                bf16x4 pk;
                #pragma unroll
                for (int reg = 0; reg < 4; reg++)
                    pk[reg] = (bf16_t)(acc[mi][ni][reg] + bcol);
                const int lc = col - vbase;
                *reinterpret_cast<bf16x4*>(&smem[lc * 260 + rl0]) = pk;
            }
        }
    }
    const int nv = n0 + BN - 2048;
    if (nv > 0) {
        __builtin_amdgcn_s_barrier();
        const int nvc = nv < BN ? nv : BN;
        const int lcb = tid >> 5;            // 0..15
        const int rl  = (tid & 31) * 8;      // 0..248
        const int b   = m0 >> 11;
        const int s   = (m0 & 2047) + rl;
        for (int j = 0; j < nvc / 16; j++) {
            const int lc = j * 16 + lcb;
            bf16x8 vv = *reinterpret_cast<const bf16x8*>(&smem[lc * 260 + rl]);
            const int col = vbase + lc;
            const int d = col & 1023;
            const int h = d >> 6, hd = d & 63;
            *reinterpret_cast<bf16x8*>(
                vtw + (((size_t)(b * HH + h)) * HDD + hd) * SS + s) = vv;
        }
    }
}

// ---------------------------------------------------------------------------
// BM=64 proj GEMM, BK=64 (grid 512 = 2/CU). Unchanged this round.
// ---------------------------------------------------------------------------
__global__ __launch_bounds__(256) void gemm_bt64(
    const bf16_t* __restrict__ A, const bf16_t* __restrict__ Bt,
    const float* __restrict__ bias, float* __restrict__ outf, int N, int K)
{
    __shared__ __align__(16) bf16_t As[2][64 * 32];
    __shared__ __align__(16) bf16_t Bs[2][128 * 32];

    const int tid  = threadIdx.x;
    const int w    = tid >> 6;
    const int lane = tid & 63;
    const int lr   = lane & 15;
    const int quad = lane >> 4;
    const int m0   = blockIdx.y * 64;
    const int n0   = blockIdx.x * 128;
    const int wm   = w >> 1;
    const int wn   = w & 1;

    f32x4 acc[2][4];
    #pragma unroll
    for (int i = 0; i < 2; i++)
        #pragma unroll
        for (int j = 0; j < 4; j++) acc[i][j] = (f32x4){0.f, 0.f, 0.f, 0.f};

    const int stgRow = lane >> 2;
    const int stgCol = (lane & 3) * 8;
    const bf16_t* aPtr = A  + (size_t)(m0 + w * 16 + stgRow) * K + stgCol;
    const bf16_t* bPtr = Bt + (size_t)(n0 + w * 32 + stgRow) * K + stgCol;
    const size_t rowSkip = (size_t)16 * K;

    for (int ks = 0; ks < K; ks += 64) {
        __syncthreads();
        #pragma unroll
        for (int s = 0; s < 2; s++) {
            const int ko = ks + s * 32;
            gl_lds16(aPtr + ko,           &As[s][w * 512]);
            gl_lds16(bPtr + ko,           &Bs[s][w * 1024]);
            gl_lds16(bPtr + rowSkip + ko, &Bs[s][w * 1024 + 512]);
        }
        __syncthreads();

        #pragma unroll
        for (int s = 0; s < 2; s++) {
            bf16x8 af[2], bf[4];
            #pragma unroll
            for (int mi = 0; mi < 2; mi++)
                af[mi] = *reinterpret_cast<const bf16x8*>(&As[s][(wm * 32 + mi * 16 + lr) * 32 + quad * 8]);
            #pragma unroll
            for (int ni = 0; ni < 4; ni++)
                bf[ni] = *reinterpret_cast<const bf16x8*>(&Bs[s][(wn * 64 + ni * 16 + lr) * 32 + quad * 8]);
            #pragma unroll
            for (int mi = 0; mi < 2; mi++)
                #pragma unroll
                for (int ni = 0; ni < 4; ni++)
                    acc[mi][ni] = __builtin_amdgcn_mfma_f32_16x16x32_bf16(af[mi], bf[ni], acc[mi][ni], 0, 0, 0);
        }
    }

    #pragma unroll
    for (int mi = 0; mi < 2; mi++)
        #pragma unroll
        for (int ni = 0; ni < 4; ni++)
            #pragma unroll
            for (int reg = 0; reg < 4; reg++) {
                int row = m0 + wm * 32 + mi * 16 + quad * 4 + reg;
                int col = n0 + wn * 64 + ni * 16 + lr;
                outf[(size_t)row * N + col] = acc[mi][ni][reg] + bias[col];
            }
}

// ---------------------------------------------------------------------------
// Flash attention v9 (R5):
//   - XCD-aware swizzle: all 16 q-blocks of a bh pinned to XCD bh&7
//     (4 bh/XCD, K+V working set 2MB < 4MB L2 -> K/V L2-resident).
//   - V LDS layout permuted (middle two quads of each 16-block swapped,
//     row pitch 68 -> 72 for 16B alignment): PV B-fragment is ONE aligned
//     ds_read_b128 (was 2x ds_read_b64 + shuffle).
//   - setprio(1) around QK and PV MFMA clusters (T5, attn-proven).
//   Everything else (32x32x16, 2-way kv-split, register P, double-buffered
//   K/V, one barrier/iter) unchanged.
// ---------------------------------------------------------------------------
__global__ __launch_bounds__(512, 4) void attn_kernel(
    const bf16_t* __restrict__ qws, const bf16_t* __restrict__ kws,
    const bf16_t* __restrict__ vtws, bf16_t* __restrict__ ob)
{
    __shared__ __align__(16) bf16_t smem[35072];   // 70144 B -> 2 blocks/CU
    bf16_t* Ks = smem;                 // 2 buf x 2 g x 520*8 = 16640 el
    bf16_t* Vs = smem + 16640;         // 2 buf x 2 g x 64*72 = 18432 el

    const int tid  = threadIdx.x;
    const int w    = tid >> 6;
    const int g    = w >> 2;
    const int wg   = w & 3;
    const int lane = tid & 63;
    const int ln31 = lane & 31;
    const int ln5  = lane >> 5;

    // XCD swizzle: flat = bh&7 + 8*((bh>>3)*16 + qb)  (bijective, 512 blocks)
    const int flat = blockIdx.y * 16 + blockIdx.x;
    const int t2 = flat >> 3;
    const int bh = (t2 >> 4) * 8 + (flat & 7);
    const int qb = t2 & 15;
    const int b  = bh >> 4;
    const int h  = bh & 15;

    const bf16_t* Qh  = qws  + (size_t)bh * SS * HDD;
    const bf16_t* Kh  = kws  + (size_t)bh * SS * HDD;
    const bf16_t* Vth = vtws + (size_t)bh * HDD * SS;

    const int q0w    = qb * 128 + wg * 32;
    const int kvbase = g * 1024;

    bf16x8 aq[4];
    #pragma unroll
    for (int f = 0; f < 4; f++)
        aq[f] = *(const bf16x8*)(Qh + (size_t)(q0w + ln31) * HDD + f * 16 + ln5 * 8);

    const int gtid = tid & 255;
    const int sc = gtid & 7;
    const int sr = gtid >> 3;
    // permuted V column base within a row: block (sc>>1)*16, quad offset
    const int vcol = (sc >> 1) * 16 + (sc & 1) * 4;

    {
        const int ko = g * 520;
        const int vo = g * 4608;
        bf16x8 k0 = *(const bf16x8*)(Kh  + (size_t)(kvbase + sr     ) * HDD + sc * 8);
        bf16x8 k1 = *(const bf16x8*)(Kh  + (size_t)(kvbase + sr + 32) * HDD + sc * 8);
        bf16x8 v0 = *(const bf16x8*)(Vth + (size_t)(sr     ) * SS + kvbase + sc * 8);
        bf16x8 v1 = *(const bf16x8*)(Vth + (size_t)(sr + 32) * SS + kvbase + sc * 8);
        *reinterpret_cast<bf16x8*>(&Ks[(ko + sc * 65 + sr     ) * 8]) = k0;
        *reinterpret_cast<bf16x8*>(&Ks[(ko + sc * 65 + sr + 32) * 8]) = k1;
        bf16_t* vd0 = &Vs[vo + (sr     ) * 72 + vcol];
        bf16_t* vd1 = &Vs[vo + (sr + 32) * 72 + vcol];
        *reinterpret_cast<bf16x4*>(vd0)     = __builtin_shufflevector(v0, v0, 0,1,2,3);
        *reinterpret_cast<bf16x4*>(vd0 + 8) = __builtin_shufflevector(v0, v0, 4,5,6,7);
        *reinterpret_cast<bf16x4*>(vd1)     = __builtin_shufflevector(v1, v1, 0,1,2,3);
        *reinterpret_cast<bf16x4*>(vd1 + 8) = __builtin_shufflevector(v1, v1, 4,5,6,7);
    }
    __syncthreads();

    float l = 0.f;
    f32x16 o[2];
    #pragma unroll
    for (int nh = 0; nh < 2; nh++)
        #pragma unroll
        for (int r = 0; r < 16; r++) o[nh][r] = 0.f;

    int buf = 0;
    for (int it = 0; it < 16; ++it) {
        const int ko = buf * 1040 + g * 520;
        const int vo = buf * 9216 + g * 4608;

        f32x16 sfr[2];
        __builtin_amdgcn_s_setprio(1);
        #pragma unroll
        for (int ni = 0; ni < 2; ni++) {
            #pragma unroll
            for (int r = 0; r < 16; r++) sfr[ni][r] = 0.f;
            #pragma unroll
            for (int f = 0; f < 4; f++) {
                bf16x8 kb = *reinterpret_cast<const bf16x8*>(
                    &Ks[(ko + (2 * f + ln5) * 65 + ni * 32 + ln31) * 8]);
                sfr[ni] = __builtin_amdgcn_mfma_f32_32x32x16_bf16(kb, aq[f], sfr[ni], 0, 0, 0);
            }
        }
        __builtin_amdgcn_s_setprio(0);

        bf16x8 nk0, nk1, nv0, nv1;
        const bool more = (it + 1 < 16);
        if (more) {
            const int kvn = kvbase + (it + 1) * 64;
            nk0 = *(const bf16x8*)(Kh  + (size_t)(kvn + sr     ) * HDD + sc * 8);
            nk1 = *(const bf16x8*)(Kh  + (size_t)(kvn + sr + 32) * HDD + sc * 8);
            nv0 = *(const bf16x8*)(Vth + (size_t)(sr     ) * SS + kvn + sc * 8);
            nv1 = *(const bf16x8*)(Vth + (size_t)(sr + 32) * SS + kvn + sc * 8);
        }

        float p[2][16];
        #pragma unroll
        for (int ni = 0; ni < 2; ni++)
            #pragma unroll
            for (int r = 0; r < 16; r++) {
                p[ni][r] = __builtin_amdgcn_exp2f(sfr[ni][r]);
                l += p[ni][r];
            }

        bf16x8 ap[4];
        #pragma unroll
        for (int c16 = 0; c16 < 4; c16++)
            #pragma unroll
            for (int j = 0; j < 8; j++)
                ap[c16][j] = (bf16_t)p[c16 >> 1][(c16 & 1) * 8 + j];

        __builtin_amdgcn_s_setprio(1);
        #pragma unroll
        for (int nh = 0; nh < 2; nh++) {
            const bf16_t* vrow = &Vs[vo + (nh * 32 + ln31) * 72];
            #pragma unroll
            for (int c16 = 0; c16 < 4; c16++) {
                bf16x8 vb = *reinterpret_cast<const bf16x8*>(vrow + c16 * 16 + 8 * ln5);
                o[nh] = __builtin_amdgcn_mfma_f32_32x32x16_bf16(ap[c16], vb, o[nh], 0, 0, 0);
            }
        }
        __builtin_amdgcn_s_setprio(0);

        if (more) {
            const int ko1 = (buf ^ 1) * 1040 + g * 520;
            const int vo1 = (buf ^ 1) * 9216 + g * 4608;
            *reinterpret_cast<bf16x8*>(&Ks[(ko1 + sc * 65 + sr     ) * 8]) = nk0;
            *reinterpret_cast<bf16x8*>(&Ks[(ko1 + sc * 65 + sr + 32) * 8]) = nk1;
            bf16_t* vd0 = &Vs[vo1 + (sr     ) * 72 + vcol];
            bf16_t* vd1 = &Vs[vo1 + (sr + 32) * 72 + vcol];
            *reinterpret_cast<bf16x4*>(vd0)     = __builtin_shufflevector(nv0, nv0, 0,1,2,3);
            *reinterpret_cast<bf16x4*>(vd0 + 8) = __builtin_shufflevector(nv0, nv0, 4,5,6,7);
            *reinterpret_cast<bf16x4*>(vd1)     = __builtin_shufflevector(nv1, nv1, 0,1,2,3);
            *reinterpret_cast<bf16x4*>(vd1 + 8) = __builtin_shufflevector(nv1, nv1, 4,5,6,7);
        }
        __syncthreads();
        buf ^= 1;
    }

    l += __shfl_xor(l, 32, 64);

    __syncthreads();
    float* Of = (float*)smem;
    float* Lf = (float*)(smem + 16384);
    if (ln5 == 0) Lf[g * 128 + wg * 32 + ln31] = l;
    if (g == 1) {
        #pragma unroll
        for (int nh = 0; nh < 2; nh++)
            #pragma unroll
            for (int r = 0; r < 16; r++) {
                const int q = (r & 3) + 8 * (r >> 2) + 4 * ln5;
                Of[(wg * 32 + q) * 64 + nh * 32 + ln31] = o[nh][r];
            }
    }
    __syncthreads();
    if (g == 0) {
        float inv[16];
        #pragma unroll
        for (int r = 0; r < 16; r++) {
            const int q = (r & 3) + 8 * (r >> 2) + 4 * ln5;
            inv[r] = 1.f / (Lf[wg * 32 + q] + Lf[128 + wg * 32 + q]);
        }
        #pragma unroll
        for (int nh = 0; nh < 2; nh++)
            #pragma unroll
            for (int r = 0; r < 16; r++) {
                const int q  = (r & 3) + 8 * (r >> 2) + 4 * ln5;
                const int hd = nh * 32 + ln31;
                float val = (o[nh][r] + Of[(wg * 32 + q) * 64 + hd]) * inv[r];
                ob[((size_t)b * SS + q0w + q) * DD + h * HDD + hd] = (bf16_t)val;
            }
    }
}

// ---------------------------------------------------------------------------
extern "C" void kernel_launch(void* const* d_in, const int* in_sizes, int n_in,
                              void* d_out, int out_size, void* d_ws, size_t ws_size,
                              hipStream_t stream) {
    const float* x     = (const float*)d_in[0];
    const float* Wqkv  = (const float*)d_in[1];
    const float* bqkv  = (const float*)d_in[2];
    const float* Wproj = (const float*)d_in[3];
    const float* bproj = (const float*)d_in[4];
    float* out = (float*)d_out;

    const size_t NEL = (size_t)MM * DD;   // 4194304
    bf16_t* qws    = (bf16_t*)d_ws;
    bf16_t* kws    = qws  + NEL;
    bf16_t* vtws   = kws  + NEL;
    bf16_t* xb     = vtws + NEL;          // aliased: xb then ows
    bf16_t* ows    = xb;
    bf16_t* wqkvt  = xb + NEL;
    bf16_t* wprojt = wqkvt + (size_t)NQKV * DD;

    prep<<<6144, 256, 0, stream>>>(x, Wqkv, Wproj, xb, wqkvt, wprojt);

    gemm_qkv<<<dim3(NQKV / 192, MM / 256), 512, 0, stream>>>(
        xb, wqkvt, bqkv, qws, kws, vtws);

    attn_kernel<<<dim3(SS / 128, BB * HH), 512, 0, stream>>>(qws, kws, vtws, ows);

    gemm_bt64<<<dim3(DD / 128, MM / 64), 256, 0, stream>>>(
        ows, wprojt, bproj, out, DD, DD);
}

// Round 6
// 172.316 us; speedup vs baseline: 1.1174x; 1.0002x over previous
//
#include <hip/hip_runtime.h>
#include <hip/hip_bf16.h>

// Problem constants
#define BB 2
#define SS 2048
#define DD 1024
#define HH 16
#define HDD 64
#define MM (BB*SS)          // 4096
#define NQKV (3*DD)         // 3072
#define SCALE 0.125f        // HD^-0.5
#define QPRESCALE 0.18033688f   // SCALE * log2(e), folded into Q at GEMM epilogue

typedef __bf16 bf16_t;
typedef bf16_t bf16x4 __attribute__((ext_vector_type(4)));
typedef bf16_t bf16x8 __attribute__((ext_vector_type(8)));
typedef float f32x4 __attribute__((ext_vector_type(4)));
typedef float f32x16 __attribute__((ext_vector_type(16)));

// ---------------------------------------------------------------------------
// global -> LDS direct DMA, 16B per lane.
// ---------------------------------------------------------------------------
__device__ __forceinline__ void gl_lds16(const bf16_t* g, bf16_t* l) {
    __builtin_amdgcn_global_load_lds(
        (const __attribute__((address_space(1))) unsigned int*)(uintptr_t)g,
        (__attribute__((address_space(3))) unsigned int*)(uintptr_t)l,
        16, 0, 0);
}

__device__ __forceinline__ f32x4 MF(bf16x8 a, bf16x8 b, f32x4 c) {
    return __builtin_amdgcn_mfma_f32_16x16x32_bf16(a, b, c, 0, 0, 0);
}

// ---------------------------------------------------------------------------
// Fused prep kernel (one launch):
//   blocks [0,2048): convert x f32 -> bf16 (8 elems/thread)
//   blocks [2048,5120): transpose Wqkv -> wqkvt [3072][1024] bf16 (96x32 tiles)
//   blocks [5120,6144): transpose Wproj -> wprojt [1024][1024] bf16 (32x32 tiles)
// ---------------------------------------------------------------------------
__global__ __launch_bounds__(256) void prep(
    const float* __restrict__ x, const float* __restrict__ Wqkv,
    const float* __restrict__ Wproj, bf16_t* __restrict__ xb,
    bf16_t* __restrict__ wqkvt, bf16_t* __restrict__ wprojt)
{
    const int bx = blockIdx.x;
    if (bx < 2048) {
        int i = (bx * 256 + threadIdx.x) * 8;
        float4 a = *(const float4*)(x + i);
        float4 b = *(const float4*)(x + i + 4);
        bf16x8 v;
        v[0]=(bf16_t)a.x; v[1]=(bf16_t)a.y; v[2]=(bf16_t)a.z; v[3]=(bf16_t)a.w;
        v[4]=(bf16_t)b.x; v[5]=(bf16_t)b.y; v[6]=(bf16_t)b.z; v[7]=(bf16_t)b.w;
        *reinterpret_cast<bf16x8*>(xb + i) = v;
        return;
    }
    __shared__ float tile[32][33];
    const float* src; bf16_t* dst; int C, bxl, byl;
    if (bx < 5120) {
        int t = bx - 2048;
        byl = t / 96; bxl = t - byl * 96;   // 96 not pow2 -> real division
        src = Wqkv;  dst = wqkvt;  C = NQKV;
    } else {
        int t = bx - 5120;
        byl = t >> 5; bxl = t & 31;
        src = Wproj; dst = wprojt; C = DD;
    }
    const int R = DD;
    const int tx = threadIdx.x & 31, ty = threadIdx.x >> 5;
    const int r0 = byl * 32, c0 = bxl * 32;
    #pragma unroll
    for (int i = 0; i < 32; i += 8)
        tile[ty + i][tx] = src[(size_t)(r0 + ty + i) * C + c0 + tx];
    __syncthreads();
    #pragma unroll
    for (int i = 0; i < 32; i += 8)
        dst[(size_t)(c0 + ty + i) * R + r0 + tx] = (bf16_t)tile[tx][ty + i];
}

// ---------------------------------------------------------------------------
// QKV GEMM (unchanged, verified): BM=256, BN=192, BK=32, 8 waves,
// 256 blocks = 1/CU, XCD-swizzled, counted-vmcnt 3-buffer pipeline.
// ---------------------------------------------------------------------------
__global__ __launch_bounds__(512, 2) void gemm_qkv(
    const bf16_t* __restrict__ A, const bf16_t* __restrict__ Bt,
    const float* __restrict__ bias,
    bf16_t* __restrict__ qw, bf16_t* __restrict__ kw, bf16_t* __restrict__ vtw)
{
    constexpr int K  = DD;          // 1024
    constexpr int BM = 256, BN = 192, BK = 32;
    constexpr int NT = K / BK;      // 32

    __shared__ __align__(16) bf16_t smem[50176];   // 100352 B -> 1 block/CU
    bf16_t* const Ab[3] = { smem, smem + 8192, smem + 16384 };
    bf16_t* const Bb[3] = { smem + 24576, smem + 30720, smem + 36864 };

    const int tid  = threadIdx.x;
    const int w    = tid >> 6;
    const int lane = tid & 63;
    const int lr   = lane & 15;
    const int quad = lane >> 4;
    const int wm   = w >> 2;
    const int wn   = w & 3;

    const int flat = blockIdx.y * 16 + blockIdx.x;
    const int swz  = (flat & 7) * 32 + (flat >> 3);
    const int m0   = (swz >> 4) * BM;
    const int n0   = (swz & 15) * BN;

    f32x4 acc[8][3];
    #pragma unroll
    for (int mi = 0; mi < 8; mi++)
        #pragma unroll
        for (int ni = 0; ni < 3; ni++)
            acc[mi][ni] = (f32x4){0.f, 0.f, 0.f, 0.f};

    const int ca0 = tid,        ca1 = tid + 512;
    const int cb0 = tid,        cb1 = tid + 256;
    const bf16_t* aG0 = A  + (size_t)(m0 + (ca0 >> 2)) * K + (ca0 & 3) * 8;
    const bf16_t* aG1 = A  + (size_t)(m0 + (ca1 >> 2)) * K + (ca1 & 3) * 8;
    const bf16_t* bG0 = Bt + (size_t)(n0 + (cb0 >> 2)) * K + (cb0 & 3) * 8;
    const bf16_t* bG1 = Bt + (size_t)(n0 + (cb1 >> 2)) * K + (cb1 & 3) * 8;

    auto stage = [&](int kt, bf16_t* Ad, bf16_t* Bd) {
        const int ko = kt * BK;
        gl_lds16(aG0 + ko, Ad + ca0 * 8);
        gl_lds16(aG1 + ko, Ad + ca1 * 8);
        gl_lds16(bG0 + ko, Bd + cb0 * 8);
        gl_lds16(bG1 + ko, Bd + cb1 * 8);
    };

    stage(0, Ab[0], Bb[0]);
    stage(1, Ab[1], Bb[1]);
    asm volatile("s_waitcnt vmcnt(4)" ::: "memory");
    __builtin_amdgcn_s_barrier();
    __builtin_amdgcn_sched_barrier(0);

    const int aOff = (wm * 128 + lr) * BK + quad * 8;
    const int bOff = (wn * 48  + lr) * BK + quad * 8;

    auto tileStep = [&](int t, const bf16_t* Ac, const bf16_t* Bc,
                        bf16_t* An, bf16_t* Bn) {
        bf16x8 af[8], bk[3];
        #pragma unroll
        for (int mi = 0; mi < 8; mi++)
            af[mi] = *(const bf16x8*)(Ac + aOff + mi * 16 * BK);
        #pragma unroll
        for (int ni = 0; ni < 3; ni++)
            bk[ni] = *(const bf16x8*)(Bc + bOff + ni * 16 * BK);
        if (t < NT - 2) stage(t + 2, An, Bn);
        __builtin_amdgcn_sched_barrier(0);
        __builtin_amdgcn_s_setprio(1);
        #pragma unroll
        for (int mi = 0; mi < 8; mi++)
            #pragma unroll
            for (int ni = 0; ni < 3; ni++)
                acc[mi][ni] = MF(af[mi], bk[ni], acc[mi][ni]);
        __builtin_amdgcn_s_setprio(0);
        __builtin_amdgcn_sched_barrier(0);
        if (t < NT - 2)       asm volatile("s_waitcnt vmcnt(4)" ::: "memory");
        else if (t == NT - 2) asm volatile("s_waitcnt vmcnt(0)" ::: "memory");
        __builtin_amdgcn_s_barrier();
        __builtin_amdgcn_sched_barrier(0);
    };

    #pragma unroll 1
    for (int tt = 0; tt < NT - 2; tt += 3) {
        tileStep(tt,     Ab[0], Bb[0], Ab[2], Bb[2]);
        tileStep(tt + 1, Ab[1], Bb[1], Ab[0], Bb[0]);
        tileStep(tt + 2, Ab[2], Bb[2], Ab[1], Bb[1]);
    }
    tileStep(NT - 2, Ab[0], Bb[0], nullptr, nullptr);
    tileStep(NT - 1, Ab[1], Bb[1], nullptr, nullptr);

    __builtin_amdgcn_s_barrier();

    const int colBase = n0 + wn * 48;
    const int vbase   = (n0 < 2048) ? 2048 : n0;
    #pragma unroll
    for (int mi = 0; mi < 8; mi++) {
        const int rl0 = wm * 128 + mi * 16 + quad * 4;
        #pragma unroll
        for (int ni = 0; ni < 3; ni++) {
            const int col = colBase + ni * 16 + lr;
            const float bcol = bias[col];
            const int which = col >> 10;
            const int d = col & 1023;
            const int h = d >> 6, hd = d & 63;
            if (which == 0) {
                #pragma unroll
                for (int reg = 0; reg < 4; reg++) {
                    const int row = m0 + rl0 + reg;
                    const int b = row >> 11, s = row & 2047;
                    qw[(((size_t)(b * HH + h)) * SS + s) * HDD + hd] =
                        (bf16_t)((acc[mi][ni][reg] + bcol) * QPRESCALE);
                }
            } else if (which == 1) {
                #pragma unroll
                for (int reg = 0; reg < 4; reg++) {
                    const int row = m0 + rl0 + reg;
                    const int b = row >> 11, s = row & 2047;
                    kw[(((size_t)(b * HH + h)) * SS + s) * HDD + hd] =
                        (bf16_t)(acc[mi][ni][reg] + bcol);
                }
            } else {
                bf16x4 pk;
                #pragma unroll
                for (int reg = 0; reg < 4; reg++)
                    pk[reg] = (bf16_t)(acc[mi][ni][reg] + bcol);
                const int lc = col - vbase;
                *reinterpret_cast<bf16x4*>(&smem[lc * 260 + rl0]) = pk;
            }
        }
    }
    const int nv = n0 + BN - 2048;
    if (nv > 0) {
        __builtin_amdgcn_s_barrier();
        const int nvc = nv < BN ? nv : BN;
        const int lcb = tid >> 5;
        const int rl  = (tid & 31) * 8;
        const int b   = m0 >> 11;
        const int s   = (m0 & 2047) + rl;
        for (int j = 0; j < nvc / 16; j++) {
            const int lc = j * 16 + lcb;
            bf16x8 vv = *reinterpret_cast<const bf16x8*>(&smem[lc * 260 + rl]);
            const int col = vbase + lc;
            const int d = col & 1023;
            const int h = d >> 6, hd = d & 63;
            *reinterpret_cast<bf16x8*>(
                vtw + (((size_t)(b * HH + h)) * HDD + hd) * SS + s) = vv;
        }
    }
}

// ---------------------------------------------------------------------------
// Proj GEMM (R6 rewrite): BM=128, BN=128, BK=32, 512 threads = 8 waves
// (2M x 4N, wave tile 64x32), grid 8x32 = 256 blocks = 1/CU, XCD swizzle.
// Same counted-vmcnt 3-buffer pipeline as gemm_qkv (2 loads/thread/stage ->
// vmcnt(2)). LDS 48KB -> 3 blocks/CU; launch_bounds(512,6) caps VGPR at 85.
// ---------------------------------------------------------------------------
__global__ __launch_bounds__(512, 6) void gemm_proj(
    const bf16_t* __restrict__ A, const bf16_t* __restrict__ Bt,
    const float* __restrict__ bias, float* __restrict__ outf)
{
    constexpr int K  = DD;          // 1024
    constexpr int N  = DD;
    constexpr int BM = 128, BN = 128, BK = 32;
    constexpr int NT = K / BK;      // 32

    __shared__ __align__(16) bf16_t smem[24576];   // 49152 B -> 3 blocks/CU
    bf16_t* const Ab[3] = { smem, smem + 4096, smem + 8192 };
    bf16_t* const Bb[3] = { smem + 12288, smem + 16384, smem + 20480 };

    const int tid  = threadIdx.x;
    const int w    = tid >> 6;
    const int lane = tid & 63;
    const int lr   = lane & 15;
    const int quad = lane >> 4;
    const int wm   = w >> 2;        // 0..1 -> rows wm*64..+63
    const int wn   = w & 3;         // 0..3 -> cols wn*32..+31

    // XCD swizzle: 256 blocks, XCD k gets 4 consecutive M-panels (x 8 N).
    const int flat = blockIdx.y * 8 + blockIdx.x;
    const int swz  = (flat & 7) * 32 + (flat >> 3);
    const int m0   = (swz >> 3) * BM;
    const int n0   = (swz & 7) * BN;

    f32x4 acc[4][2];
    #pragma unroll
    for (int mi = 0; mi < 4; mi++)
        #pragma unroll
        for (int ni = 0; ni < 2; ni++)
            acc[mi][ni] = (f32x4){0.f, 0.f, 0.f, 0.f};

    // staging: A/B each 128 rows x 4 chunks = 512 chunks of 16B, 1/thread.
    const bf16_t* aG = A  + (size_t)(m0 + (tid >> 2)) * K + (tid & 3) * 8;
    const bf16_t* bG = Bt + (size_t)(n0 + (tid >> 2)) * K + (tid & 3) * 8;

    auto stage = [&](int kt, bf16_t* Ad, bf16_t* Bd) {
        const int ko = kt * BK;
        gl_lds16(aG + ko, Ad + tid * 8);
        gl_lds16(bG + ko, Bd + tid * 8);
    };

    stage(0, Ab[0], Bb[0]);
    stage(1, Ab[1], Bb[1]);
    asm volatile("s_waitcnt vmcnt(2)" ::: "memory");
    __builtin_amdgcn_s_barrier();
    __builtin_amdgcn_sched_barrier(0);

    const int aOff = (wm * 64 + lr) * BK + quad * 8;
    const int bOff = (wn * 32 + lr) * BK + quad * 8;

    auto tileStep = [&](int t, const bf16_t* Ac, const bf16_t* Bc,
                        bf16_t* An, bf16_t* Bn) {
        bf16x8 af[4], bk[2];
        #pragma unroll
        for (int mi = 0; mi < 4; mi++)
            af[mi] = *(const bf16x8*)(Ac + aOff + mi * 16 * BK);
        #pragma unroll
        for (int ni = 0; ni < 2; ni++)
            bk[ni] = *(const bf16x8*)(Bc + bOff + ni * 16 * BK);
        if (t < NT - 2) stage(t + 2, An, Bn);
        __builtin_amdgcn_sched_barrier(0);
        __builtin_amdgcn_s_setprio(1);
        #pragma unroll
        for (int mi = 0; mi < 4; mi++)
            #pragma unroll
            for (int ni = 0; ni < 2; ni++)
                acc[mi][ni] = MF(af[mi], bk[ni], acc[mi][ni]);
        __builtin_amdgcn_s_setprio(0);
        __builtin_amdgcn_sched_barrier(0);
        if (t < NT - 2)       asm volatile("s_waitcnt vmcnt(2)" ::: "memory");
        else if (t == NT - 2) asm volatile("s_waitcnt vmcnt(0)" ::: "memory");
        __builtin_amdgcn_s_barrier();
        __builtin_amdgcn_sched_barrier(0);
    };

    #pragma unroll 1
    for (int tt = 0; tt < NT - 2; tt += 3) {
        tileStep(tt,     Ab[0], Bb[0], Ab[2], Bb[2]);
        tileStep(tt + 1, Ab[1], Bb[1], Ab[0], Bb[0]);
        tileStep(tt + 2, Ab[2], Bb[2], Ab[1], Bb[1]);
    }
    tileStep(NT - 2, Ab[0], Bb[0], nullptr, nullptr);   // t=30: vmcnt(0)
    tileStep(NT - 1, Ab[1], Bb[1], nullptr, nullptr);   // t=31

    #pragma unroll
    for (int mi = 0; mi < 4; mi++)
        #pragma unroll
        for (int ni = 0; ni < 2; ni++) {
            const int col = n0 + wn * 32 + ni * 16 + lr;
            const float bcol = bias[col];
            #pragma unroll
            for (int reg = 0; reg < 4; reg++) {
                const int row = m0 + wm * 64 + mi * 16 + quad * 4 + reg;
                outf[(size_t)row * N + col] = acc[mi][ni][reg] + bcol;
            }
        }
}

// ---------------------------------------------------------------------------
// Flash attention v9b: R5 kernel + K/V global prefetch hoisted BEFORE the
// QK MFMA cluster (R5's sched_barrier fence pinned it after -> only ~300cy
// of cover; ahead of QK it gets ~600cy). Everything else unchanged.
// ---------------------------------------------------------------------------
__global__ __launch_bounds__(512, 4) void attn_kernel(
    const bf16_t* __restrict__ qws, const bf16_t* __restrict__ kws,
    const bf16_t* __restrict__ vtws, bf16_t* __restrict__ ob)
{
    __shared__ __align__(16) bf16_t smem[35072];   // 70144 B -> 2 blocks/CU
    bf16_t* Ks = smem;                 // 2 buf x 2 g x 520*8 = 16640 el
    bf16_t* Vs = smem + 16640;         // 2 buf x 2 g x 64*72 = 18432 el

    const int tid  = threadIdx.x;
    const int w    = tid >> 6;
    const int g    = w >> 2;
    const int wg   = w & 3;
    const int lane = tid & 63;
    const int ln31 = lane & 31;
    const int ln5  = lane >> 5;

    // XCD swizzle: all 16 q-blocks of a bh pinned to XCD bh&7.
    const int flat = blockIdx.y * 16 + blockIdx.x;
    const int t2 = flat >> 3;
    const int bh = (t2 >> 4) * 8 + (flat & 7);
    const int qb = t2 & 15;
    const int b  = bh >> 4;
    const int h  = bh & 15;

    const bf16_t* Qh  = qws  + (size_t)bh * SS * HDD;
    const bf16_t* Kh  = kws  + (size_t)bh * SS * HDD;
    const bf16_t* Vth = vtws + (size_t)bh * HDD * SS;

    const int q0w    = qb * 128 + wg * 32;
    const int kvbase = g * 1024;

    bf16x8 aq[4];
    #pragma unroll
    for (int f = 0; f < 4; f++)
        aq[f] = *(const bf16x8*)(Qh + (size_t)(q0w + ln31) * HDD + f * 16 + ln5 * 8);

    const int gtid = tid & 255;
    const int sc = gtid & 7;
    const int sr = gtid >> 3;
    const int vcol = (sc >> 1) * 16 + (sc & 1) * 4;

    {
        const int ko = g * 520;
        const int vo = g * 4608;
        bf16x8 k0 = *(const bf16x8*)(Kh  + (size_t)(kvbase + sr     ) * HDD + sc * 8);
        bf16x8 k1 = *(const bf16x8*)(Kh  + (size_t)(kvbase + sr + 32) * HDD + sc * 8);
        bf16x8 v0 = *(const bf16x8*)(Vth + (size_t)(sr     ) * SS + kvbase + sc * 8);
        bf16x8 v1 = *(const bf16x8*)(Vth + (size_t)(sr + 32) * SS + kvbase + sc * 8);
        *reinterpret_cast<bf16x8*>(&Ks[(ko + sc * 65 + sr     ) * 8]) = k0;
        *reinterpret_cast<bf16x8*>(&Ks[(ko + sc * 65 + sr + 32) * 8]) = k1;
        bf16_t* vd0 = &Vs[vo + (sr     ) * 72 + vcol];
        bf16_t* vd1 = &Vs[vo + (sr + 32) * 72 + vcol];
        *reinterpret_cast<bf16x4*>(vd0)     = __builtin_shufflevector(v0, v0, 0,1,2,3);
        *reinterpret_cast<bf16x4*>(vd0 + 8) = __builtin_shufflevector(v0, v0, 4,5,6,7);
        *reinterpret_cast<bf16x4*>(vd1)     = __builtin_shufflevector(v1, v1, 0,1,2,3);
        *reinterpret_cast<bf16x4*>(vd1 + 8) = __builtin_shufflevector(v1, v1, 4,5,6,7);
    }
    __syncthreads();

    float l = 0.f;
    f32x16 o[2];
    #pragma unroll
    for (int nh = 0; nh < 2; nh++)
        #pragma unroll
        for (int r = 0; r < 16; r++) o[nh][r] = 0.f;

    int buf = 0;
    for (int it = 0; it < 16; ++it) {
        const int ko = buf * 1040 + g * 520;
        const int vo = buf * 9216 + g * 4608;

        // K/V prefetch for it+1 issued FIRST (independent; ~600cy cover)
        bf16x8 nk0, nk1, nv0, nv1;
        const bool more = (it + 1 < 16);
        if (more) {
            const int kvn = kvbase + (it + 1) * 64;
            nk0 = *(const bf16x8*)(Kh  + (size_t)(kvn + sr     ) * HDD + sc * 8);
            nk1 = *(const bf16x8*)(Kh  + (size_t)(kvn + sr + 32) * HDD + sc * 8);
            nv0 = *(const bf16x8*)(Vth + (size_t)(sr     ) * SS + kvn + sc * 8);
            nv1 = *(const bf16x8*)(Vth + (size_t)(sr + 32) * SS + kvn + sc * 8);
        }

        f32x16 sfr[2];
        __builtin_amdgcn_s_setprio(1);
        #pragma unroll
        for (int ni = 0; ni < 2; ni++) {
            #pragma unroll
            for (int r = 0; r < 16; r++) sfr[ni][r] = 0.f;
            #pragma unroll
            for (int f = 0; f < 4; f++) {
                bf16x8 kb = *reinterpret_cast<const bf16x8*>(
                    &Ks[(ko + (2 * f + ln5) * 65 + ni * 32 + ln31) * 8]);
                sfr[ni] = __builtin_amdgcn_mfma_f32_32x32x16_bf16(kb, aq[f], sfr[ni], 0, 0, 0);
            }
        }
        __builtin_amdgcn_s_setprio(0);

        float p[2][16];
        #pragma unroll
        for (int ni = 0; ni < 2; ni++)
            #pragma unroll
            for (int r = 0; r < 16; r++) {
                p[ni][r] = __builtin_amdgcn_exp2f(sfr[ni][r]);
                l += p[ni][r];
            }

        bf16x8 ap[4];
        #pragma unroll
        for (int c16 = 0; c16 < 4; c16++)
            #pragma unroll
            for (int j = 0; j < 8; j++)
                ap[c16][j] = (bf16_t)p[c16 >> 1][(c16 & 1) * 8 + j];

        __builtin_amdgcn_s_setprio(1);
        #pragma unroll
        for (int nh = 0; nh < 2; nh++) {
            const bf16_t* vrow = &Vs[vo + (nh * 32 + ln31) * 72];
            #pragma unroll
            for (int c16 = 0; c16 < 4; c16++) {
                bf16x8 vb = *reinterpret_cast<const bf16x8*>(vrow + c16 * 16 + 8 * ln5);
                o[nh] = __builtin_amdgcn_mfma_f32_32x32x16_bf16(ap[c16], vb, o[nh], 0, 0, 0);
            }
        }
        __builtin_amdgcn_s_setprio(0);

        if (more) {
            const int ko1 = (buf ^ 1) * 1040 + g * 520;
            const int vo1 = (buf ^ 1) * 9216 + g * 4608;
            *reinterpret_cast<bf16x8*>(&Ks[(ko1 + sc * 65 + sr     ) * 8]) = nk0;
            *reinterpret_cast<bf16x8*>(&Ks[(ko1 + sc * 65 + sr + 32) * 8]) = nk1;
            bf16_t* vd0 = &Vs[vo1 + (sr     ) * 72 + vcol];
            bf16_t* vd1 = &Vs[vo1 + (sr + 32) * 72 + vcol];
            *reinterpret_cast<bf16x4*>(vd0)     = __builtin_shufflevector(nv0, nv0, 0,1,2,3);
            *reinterpret_cast<bf16x4*>(vd0 + 8) = __builtin_shufflevector(nv0, nv0, 4,5,6,7);
            *reinterpret_cast<bf16x4*>(vd1)     = __builtin_shufflevector(nv1, nv1, 0,1,2,3);
            *reinterpret_cast<bf16x4*>(vd1 + 8) = __builtin_shufflevector(nv1, nv1, 4,5,6,7);
        }
        __syncthreads();
        buf ^= 1;
    }

    l += __shfl_xor(l, 32, 64);

    __syncthreads();
    float* Of = (float*)smem;
    float* Lf = (float*)(smem + 16384);
    if (ln5 == 0) Lf[g * 128 + wg * 32 + ln31] = l;
    if (g == 1) {
        #pragma unroll
        for (int nh = 0; nh < 2; nh++)
            #pragma unroll
            for (int r = 0; r < 16; r++) {
                const int q = (r & 3) + 8 * (r >> 2) + 4 * ln5;
                Of[(wg * 32 + q) * 64 + nh * 32 + ln31] = o[nh][r];
            }
    }
    __syncthreads();
    if (g == 0) {
        float inv[16];
        #pragma unroll
        for (int r = 0; r < 16; r++) {
            const int q = (r & 3) + 8 * (r >> 2) + 4 * ln5;
            inv[r] = 1.f / (Lf[wg * 32 + q] + Lf[128 + wg * 32 + q]);
        }
        #pragma unroll
        for (int nh = 0; nh < 2; nh++)
            #pragma unroll
            for (int r = 0; r < 16; r++) {
                const int q  = (r & 3) + 8 * (r >> 2) + 4 * ln5;
                const int hd = nh * 32 + ln31;
                float val = (o[nh][r] + Of[(wg * 32 + q) * 64 + hd]) * inv[r];
                ob[((size_t)b * SS + q0w + q) * DD + h * HDD + hd] = (bf16_t)val;
            }
    }
}

// ---------------------------------------------------------------------------
extern "C" void kernel_launch(void* const* d_in, const int* in_sizes, int n_in,
                              void* d_out, int out_size, void* d_ws, size_t ws_size,
                              hipStream_t stream) {
    const float* x     = (const float*)d_in[0];
    const float* Wqkv  = (const float*)d_in[1];
    const float* bqkv  = (const float*)d_in[2];
    const float* Wproj = (const float*)d_in[3];
    const float* bproj = (const float*)d_in[4];
    float* out = (float*)d_out;

    const size_t NEL = (size_t)MM * DD;   // 4194304
    bf16_t* qws    = (bf16_t*)d_ws;
    bf16_t* kws    = qws  + NEL;
    bf16_t* vtws   = kws  + NEL;
    bf16_t* xb     = vtws + NEL;          // aliased: xb then ows
    bf16_t* ows    = xb;
    bf16_t* wqkvt  = xb + NEL;
    bf16_t* wprojt = wqkvt + (size_t)NQKV * DD;

    prep<<<6144, 256, 0, stream>>>(x, Wqkv, Wproj, xb, wqkvt, wprojt);

    gemm_qkv<<<dim3(NQKV / 192, MM / 256), 512, 0, stream>>>(
        xb, wqkvt, bqkv, qws, kws, vtws);

    attn_kernel<<<dim3(SS / 128, BB * HH), 512, 0, stream>>>(qws, kws, vtws, ows);

    gemm_proj<<<dim3(DD / 128, MM / 128), 512, 0, stream>>>(
        ows, wprojt, bproj, out);
}

// Round 7
// 169.696 us; speedup vs baseline: 1.1347x; 1.0154x over previous
//
#include <hip/hip_runtime.h>
#include <hip/hip_bf16.h>

// Problem constants
#define BB 2
#define SS 2048
#define DD 1024
#define HH 16
#define HDD 64
#define MM (BB*SS)          // 4096
#define NQKV (3*DD)         // 3072
#define SCALE 0.125f        // HD^-0.5
#define QPRESCALE 0.18033688f   // SCALE * log2(e), folded into Q at GEMM epilogue

typedef __bf16 bf16_t;
typedef bf16_t bf16x4 __attribute__((ext_vector_type(4)));
typedef bf16_t bf16x8 __attribute__((ext_vector_type(8)));
typedef float f32x4 __attribute__((ext_vector_type(4)));
typedef float f32x16 __attribute__((ext_vector_type(16)));

// ---------------------------------------------------------------------------
// global -> LDS direct DMA, 16B per lane.
// ---------------------------------------------------------------------------
__device__ __forceinline__ void gl_lds16(const bf16_t* g, bf16_t* l) {
    __builtin_amdgcn_global_load_lds(
        (const __attribute__((address_space(1))) unsigned int*)(uintptr_t)g,
        (__attribute__((address_space(3))) unsigned int*)(uintptr_t)l,
        16, 0, 0);
}

__device__ __forceinline__ f32x4 MF(bf16x8 a, bf16x8 b, f32x4 c) {
    return __builtin_amdgcn_mfma_f32_16x16x32_bf16(a, b, c, 0, 0, 0);
}

// ---------------------------------------------------------------------------
// Fused prep kernel (one launch):
//   blocks [0,2048): convert x f32 -> bf16 (8 elems/thread)
//   blocks [2048,5120): transpose Wqkv -> wqkvt [3072][1024] bf16 (96x32 tiles)
//   blocks [5120,6144): transpose Wproj -> wprojt [1024][1024] bf16 (32x32 tiles)
// ---------------------------------------------------------------------------
__global__ __launch_bounds__(256) void prep(
    const float* __restrict__ x, const float* __restrict__ Wqkv,
    const float* __restrict__ Wproj, bf16_t* __restrict__ xb,
    bf16_t* __restrict__ wqkvt, bf16_t* __restrict__ wprojt)
{
    const int bx = blockIdx.x;
    if (bx < 2048) {
        int i = (bx * 256 + threadIdx.x) * 8;
        float4 a = *(const float4*)(x + i);
        float4 b = *(const float4*)(x + i + 4);
        bf16x8 v;
        v[0]=(bf16_t)a.x; v[1]=(bf16_t)a.y; v[2]=(bf16_t)a.z; v[3]=(bf16_t)a.w;
        v[4]=(bf16_t)b.x; v[5]=(bf16_t)b.y; v[6]=(bf16_t)b.z; v[7]=(bf16_t)b.w;
        *reinterpret_cast<bf16x8*>(xb + i) = v;
        return;
    }
    __shared__ float tile[32][33];
    const float* src; bf16_t* dst; int C, bxl, byl;
    if (bx < 5120) {
        int t = bx - 2048;
        byl = t / 96; bxl = t - byl * 96;   // 96 not pow2 -> real division
        src = Wqkv;  dst = wqkvt;  C = NQKV;
    } else {
        int t = bx - 5120;
        byl = t >> 5; bxl = t & 31;
        src = Wproj; dst = wprojt; C = DD;
    }
    const int R = DD;
    const int tx = threadIdx.x & 31, ty = threadIdx.x >> 5;
    const int r0 = byl * 32, c0 = bxl * 32;
    #pragma unroll
    for (int i = 0; i < 32; i += 8)
        tile[ty + i][tx] = src[(size_t)(r0 + ty + i) * C + c0 + tx];
    __syncthreads();
    #pragma unroll
    for (int i = 0; i < 32; i += 8)
        dst[(size_t)(c0 + ty + i) * R + r0 + tx] = (bf16_t)tile[tx][ty + i];
}

// ---------------------------------------------------------------------------
// QKV GEMM (R7): BM=128, BN=128, BK=32, 512 threads = 8 waves (2M x 4N,
// wave tile 64x32), grid 24x32 = 768 blocks = 3/CU (LDS 48KB).
// Theory: prior 1-block/CU variants all idled the CU at each tile's
// vmcnt+barrier (MfmaUtil ~19% across 4 schedules); 3 independent blocks/CU
// give cross-block overlap (the pattern that works in attn: 2 blocks -> 77%
// combined pipe busy). Counted-vmcnt 3-buffer rotation kept (2 loads/thread
// per stage -> vmcnt(2)). XCD partition: 8m x 12n sub-grid per XCD -> 5MB
// working set ~ L2-resident. BN=128 => block never straddles q/k/v =>
// uniform epilogue branch; V^T via [128][132] LDS transpose, 16B stores.
// ---------------------------------------------------------------------------
__global__ __launch_bounds__(512, 6) void gemm_qkv(
    const bf16_t* __restrict__ A, const bf16_t* __restrict__ Bt,
    const float* __restrict__ bias,
    bf16_t* __restrict__ qw, bf16_t* __restrict__ kw, bf16_t* __restrict__ vtw)
{
    constexpr int K  = DD;          // 1024
    constexpr int BM = 128, BN = 128, BK = 32;
    constexpr int NT = K / BK;      // 32

    __shared__ __align__(16) bf16_t smem[24576];   // 49152 B -> 3 blocks/CU
    bf16_t* const Ab[3] = { smem,         smem + 4096,  smem + 8192 };
    bf16_t* const Bb[3] = { smem + 12288, smem + 16384, smem + 20480 };

    const int tid  = threadIdx.x;
    const int w    = tid >> 6;
    const int lane = tid & 63;
    const int lr   = lane & 15;
    const int quad = lane >> 4;
    const int wm   = w >> 2;        // 0..1 -> rows wm*64..+63
    const int wn   = w & 3;         // 0..3 -> cols wn*32..+31

    // XCD partition: xcd = flat&7; within XCD an 8(m) x 12(n) sub-grid.
    // XCDs arranged 4(m) x 2(n) over the 32 x 24 panel grid. Bijective.
    const int flat = blockIdx.y * 24 + blockIdx.x;
    const int xcd  = flat & 7;
    const int idx  = flat >> 3;            // 0..95
    const int m0   = ((xcd >> 1) * 8 + (idx & 7)) * BM;
    const int n0   = ((xcd & 1) * 12 + (idx >> 3)) * BN;

    f32x4 acc[4][2];
    #pragma unroll
    for (int mi = 0; mi < 4; mi++)
        #pragma unroll
        for (int ni = 0; ni < 2; ni++)
            acc[mi][ni] = (f32x4){0.f, 0.f, 0.f, 0.f};

    // staging: A/B each 128 rows x 4 chunks = 512 chunks of 16B, 1/thread.
    const bf16_t* aG = A  + (size_t)(m0 + (tid >> 2)) * K + (tid & 3) * 8;
    const bf16_t* bG = Bt + (size_t)(n0 + (tid >> 2)) * K + (tid & 3) * 8;

    auto stage = [&](int kt, bf16_t* Ad, bf16_t* Bd) {
        const int ko = kt * BK;
        gl_lds16(aG + ko, Ad + tid * 8);
        gl_lds16(bG + ko, Bd + tid * 8);
    };

    stage(0, Ab[0], Bb[0]);
    stage(1, Ab[1], Bb[1]);
    asm volatile("s_waitcnt vmcnt(2)" ::: "memory");
    __builtin_amdgcn_s_barrier();
    __builtin_amdgcn_sched_barrier(0);

    const int aOff = (wm * 64 + lr) * BK + quad * 8;
    const int bOff = (wn * 32 + lr) * BK + quad * 8;

    auto tileStep = [&](int t, const bf16_t* Ac, const bf16_t* Bc,
                        bf16_t* An, bf16_t* Bn) {
        bf16x8 af[4], bk[2];
        #pragma unroll
        for (int mi = 0; mi < 4; mi++)
            af[mi] = *(const bf16x8*)(Ac + aOff + mi * 16 * BK);
        #pragma unroll
        for (int ni = 0; ni < 2; ni++)
            bk[ni] = *(const bf16x8*)(Bc + bOff + ni * 16 * BK);
        if (t < NT - 2) stage(t + 2, An, Bn);
        __builtin_amdgcn_sched_barrier(0);
        __builtin_amdgcn_s_setprio(1);
        #pragma unroll
        for (int mi = 0; mi < 4; mi++)
            #pragma unroll
            for (int ni = 0; ni < 2; ni++)
                acc[mi][ni] = MF(af[mi], bk[ni], acc[mi][ni]);
        __builtin_amdgcn_s_setprio(0);
        __builtin_amdgcn_sched_barrier(0);
        if (t < NT - 2)       asm volatile("s_waitcnt vmcnt(2)" ::: "memory");
        else if (t == NT - 2) asm volatile("s_waitcnt vmcnt(0)" ::: "memory");
        __builtin_amdgcn_s_barrier();
        __builtin_amdgcn_sched_barrier(0);
    };

    #pragma unroll 1
    for (int tt = 0; tt < NT - 2; tt += 3) {
        tileStep(tt,     Ab[0], Bb[0], Ab[2], Bb[2]);
        tileStep(tt + 1, Ab[1], Bb[1], Ab[0], Bb[0]);
        tileStep(tt + 2, Ab[2], Bb[2], Ab[1], Bb[1]);
    }
    tileStep(NT - 2, Ab[0], Bb[0], nullptr, nullptr);   // t=30: vmcnt(0)
    tileStep(NT - 1, Ab[1], Bb[1], nullptr, nullptr);   // t=31

    // ---- epilogue (block-uniform q/k/v branch: BN=128 divides the 1024s) --
    const int which = n0 >> 10;           // 0=q, 1=k, 2=v
    const int dbase = n0 & 1023;
    const int b     = m0 >> 11;
    const int s0    = m0 & 2047;

    if (which < 2) {
        bf16_t* dst = (which == 0) ? qw : kw;
        const float scale = (which == 0) ? QPRESCALE : 1.0f;
        #pragma unroll
        for (int mi = 0; mi < 4; mi++) {
            const int rl0 = wm * 64 + mi * 16 + quad * 4;
            #pragma unroll
            for (int ni = 0; ni < 2; ni++) {
                const int col = n0 + wn * 32 + ni * 16 + lr;
                const float bcol = bias[col];
                const int d = col & 1023;
                const int h = d >> 6, hd = d & 63;
                #pragma unroll
                for (int reg = 0; reg < 4; reg++) {
                    const int s = s0 + rl0 + reg;
                    dst[(((size_t)(b * HH + h)) * SS + s) * HDD + hd] =
                        (bf16_t)((acc[mi][ni][reg] + bcol) * scale);
                }
            }
        }
    } else {
        // all-V block: transpose through LDS, then 16B stores along S
        __builtin_amdgcn_s_barrier();   // LDS reads of last tile done
        #pragma unroll
        for (int mi = 0; mi < 4; mi++) {
            const int rl0 = wm * 64 + mi * 16 + quad * 4;
            #pragma unroll
            for (int ni = 0; ni < 2; ni++) {
                const int lc = wn * 32 + ni * 16 + lr;
                const float bcol = bias[n0 + lc];
                bf16x4 pk;
                #pragma unroll
                for (int reg = 0; reg < 4; reg++)
                    pk[reg] = (bf16_t)(acc[mi][ni][reg] + bcol);
                *reinterpret_cast<bf16x4*>(&smem[lc * 132 + rl0]) = pk;
            }
        }
        __builtin_amdgcn_s_barrier();
        const int lcb = tid >> 4;            // 0..31
        const int rl  = (tid & 15) * 8;      // 0..120
        const int s   = s0 + rl;
        #pragma unroll
        for (int j = 0; j < 4; j++) {
            const int lc = j * 32 + lcb;
            bf16x8 vv = *reinterpret_cast<const bf16x8*>(&smem[lc * 132 + rl]);
            const int d = dbase + lc;
            const int h = d >> 6, hd = d & 63;
            *reinterpret_cast<bf16x8*>(
                vtw + (((size_t)(b * HH + h)) * HDD + hd) * SS + s) = vv;
        }
    }
}

// ---------------------------------------------------------------------------
// Proj GEMM (unchanged from R6): BM=128, BN=128, BK=32, 8 waves,
// 256 blocks, counted-vmcnt 3-buffer pipeline.
// ---------------------------------------------------------------------------
__global__ __launch_bounds__(512, 6) void gemm_proj(
    const bf16_t* __restrict__ A, const bf16_t* __restrict__ Bt,
    const float* __restrict__ bias, float* __restrict__ outf)
{
    constexpr int K  = DD;          // 1024
    constexpr int N  = DD;
    constexpr int BM = 128, BN = 128, BK = 32;
    constexpr int NT = K / BK;      // 32

    __shared__ __align__(16) bf16_t smem[24576];   // 49152 B -> 3 blocks/CU
    bf16_t* const Ab[3] = { smem, smem + 4096, smem + 8192 };
    bf16_t* const Bb[3] = { smem + 12288, smem + 16384, smem + 20480 };

    const int tid  = threadIdx.x;
    const int w    = tid >> 6;
    const int lane = tid & 63;
    const int lr   = lane & 15;
    const int quad = lane >> 4;
    const int wm   = w >> 2;        // 0..1 -> rows wm*64..+63
    const int wn   = w & 3;         // 0..3 -> cols wn*32..+31

    // XCD swizzle: 256 blocks, XCD k gets 4 consecutive M-panels (x 8 N).
    const int flat = blockIdx.y * 8 + blockIdx.x;
    const int swz  = (flat & 7) * 32 + (flat >> 3);
    const int m0   = (swz >> 3) * BM;
    const int n0   = (swz & 7) * BN;

    f32x4 acc[4][2];
    #pragma unroll
    for (int mi = 0; mi < 4; mi++)
        #pragma unroll
        for (int ni = 0; ni < 2; ni++)
            acc[mi][ni] = (f32x4){0.f, 0.f, 0.f, 0.f};

    const bf16_t* aG = A  + (size_t)(m0 + (tid >> 2)) * K + (tid & 3) * 8;
    const bf16_t* bG = Bt + (size_t)(n0 + (tid >> 2)) * K + (tid & 3) * 8;

    auto stage = [&](int kt, bf16_t* Ad, bf16_t* Bd) {
        const int ko = kt * BK;
        gl_lds16(aG + ko, Ad + tid * 8);
        gl_lds16(bG + ko, Bd + tid * 8);
    };

    stage(0, Ab[0], Bb[0]);
    stage(1, Ab[1], Bb[1]);
    asm volatile("s_waitcnt vmcnt(2)" ::: "memory");
    __builtin_amdgcn_s_barrier();
    __builtin_amdgcn_sched_barrier(0);

    const int aOff = (wm * 64 + lr) * BK + quad * 8;
    const int bOff = (wn * 32 + lr) * BK + quad * 8;

    auto tileStep = [&](int t, const bf16_t* Ac, const bf16_t* Bc,
                        bf16_t* An, bf16_t* Bn) {
        bf16x8 af[4], bk[2];
        #pragma unroll
        for (int mi = 0; mi < 4; mi++)
            af[mi] = *(const bf16x8*)(Ac + aOff + mi * 16 * BK);
        #pragma unroll
        for (int ni = 0; ni < 2; ni++)
            bk[ni] = *(const bf16x8*)(Bc + bOff + ni * 16 * BK);
        if (t < NT - 2) stage(t + 2, An, Bn);
        __builtin_amdgcn_sched_barrier(0);
        __builtin_amdgcn_s_setprio(1);
        #pragma unroll
        for (int mi = 0; mi < 4; mi++)
            #pragma unroll
            for (int ni = 0; ni < 2; ni++)
                acc[mi][ni] = MF(af[mi], bk[ni], acc[mi][ni]);
        __builtin_amdgcn_s_setprio(0);
        __builtin_amdgcn_sched_barrier(0);
        if (t < NT - 2)       asm volatile("s_waitcnt vmcnt(2)" ::: "memory");
        else if (t == NT - 2) asm volatile("s_waitcnt vmcnt(0)" ::: "memory");
        __builtin_amdgcn_s_barrier();
        __builtin_amdgcn_sched_barrier(0);
    };

    #pragma unroll 1
    for (int tt = 0; tt < NT - 2; tt += 3) {
        tileStep(tt,     Ab[0], Bb[0], Ab[2], Bb[2]);
        tileStep(tt + 1, Ab[1], Bb[1], Ab[0], Bb[0]);
        tileStep(tt + 2, Ab[2], Bb[2], Ab[1], Bb[1]);
    }
    tileStep(NT - 2, Ab[0], Bb[0], nullptr, nullptr);   // t=30: vmcnt(0)
    tileStep(NT - 1, Ab[1], Bb[1], nullptr, nullptr);   // t=31

    #pragma unroll
    for (int mi = 0; mi < 4; mi++)
        #pragma unroll
        for (int ni = 0; ni < 2; ni++) {
            const int col = n0 + wn * 32 + ni * 16 + lr;
            const float bcol = bias[col];
            #pragma unroll
            for (int reg = 0; reg < 4; reg++) {
                const int row = m0 + wm * 64 + mi * 16 + quad * 4 + reg;
                outf[(size_t)row * N + col] = acc[mi][ni][reg] + bcol;
            }
        }
}

// ---------------------------------------------------------------------------
// Flash attention v9b (unchanged from R6): XCD bh-pinning, permuted V LDS,
// setprio around MFMA clusters, K/V prefetch hoisted before QK.
// ---------------------------------------------------------------------------
__global__ __launch_bounds__(512, 4) void attn_kernel(
    const bf16_t* __restrict__ qws, const bf16_t* __restrict__ kws,
    const bf16_t* __restrict__ vtws, bf16_t* __restrict__ ob)
{
    __shared__ __align__(16) bf16_t smem[35072];   // 70144 B -> 2 blocks/CU
    bf16_t* Ks = smem;                 // 2 buf x 2 g x 520*8 = 16640 el
    bf16_t* Vs = smem + 16640;         // 2 buf x 2 g x 64*72 = 18432 el

    const int tid  = threadIdx.x;
    const int w    = tid >> 6;
    const int g    = w >> 2;
    const int wg   = w & 3;
    const int lane = tid & 63;
    const int ln31 = lane & 31;
    const int ln5  = lane >> 5;

    // XCD swizzle: all 16 q-blocks of a bh pinned to XCD bh&7.
    const int flat = blockIdx.y * 16 + blockIdx.x;
    const int t2 = flat >> 3;
    const int bh = (t2 >> 4) * 8 + (flat & 7);
    const int qb = t2 & 15;
    const int b  = bh >> 4;
    const int h  = bh & 15;

    const bf16_t* Qh  = qws  + (size_t)bh * SS * HDD;
    const bf16_t* Kh  = kws  + (size_t)bh * SS * HDD;
    const bf16_t* Vth = vtws + (size_t)bh * HDD * SS;

    const int q0w    = qb * 128 + wg * 32;
    const int kvbase = g * 1024;

    bf16x8 aq[4];
    #pragma unroll
    for (int f = 0; f < 4; f++)
        aq[f] = *(const bf16x8*)(Qh + (size_t)(q0w + ln31) * HDD + f * 16 + ln5 * 8);

    const int gtid = tid & 255;
    const int sc = gtid & 7;
    const int sr = gtid >> 3;
    const int vcol = (sc >> 1) * 16 + (sc & 1) * 4;

    {
        const int ko = g * 520;
        const int vo = g * 4608;
        bf16x8 k0 = *(const bf16x8*)(Kh  + (size_t)(kvbase + sr     ) * HDD + sc * 8);
        bf16x8 k1 = *(const bf16x8*)(Kh  + (size_t)(kvbase + sr + 32) * HDD + sc * 8);
        bf16x8 v0 = *(const bf16x8*)(Vth + (size_t)(sr     ) * SS + kvbase + sc * 8);
        bf16x8 v1 = *(const bf16x8*)(Vth + (size_t)(sr + 32) * SS + kvbase + sc * 8);
        *reinterpret_cast<bf16x8*>(&Ks[(ko + sc * 65 + sr     ) * 8]) = k0;
        *reinterpret_cast<bf16x8*>(&Ks[(ko + sc * 65 + sr + 32) * 8]) = k1;
        bf16_t* vd0 = &Vs[vo + (sr     ) * 72 + vcol];
        bf16_t* vd1 = &Vs[vo + (sr + 32) * 72 + vcol];
        *reinterpret_cast<bf16x4*>(vd0)     = __builtin_shufflevector(v0, v0, 0,1,2,3);
        *reinterpret_cast<bf16x4*>(vd0 + 8) = __builtin_shufflevector(v0, v0, 4,5,6,7);
        *reinterpret_cast<bf16x4*>(vd1)     = __builtin_shufflevector(v1, v1, 0,1,2,3);
        *reinterpret_cast<bf16x4*>(vd1 + 8) = __builtin_shufflevector(v1, v1, 4,5,6,7);
    }
    __syncthreads();

    float l = 0.f;
    f32x16 o[2];
    #pragma unroll
    for (int nh = 0; nh < 2; nh++)
        #pragma unroll
        for (int r = 0; r < 16; r++) o[nh][r] = 0.f;

    int buf = 0;
    for (int it = 0; it < 16; ++it) {
        const int ko = buf * 1040 + g * 520;
        const int vo = buf * 9216 + g * 4608;

        // K/V prefetch for it+1 issued FIRST (independent; ~600cy cover)
        bf16x8 nk0, nk1, nv0, nv1;
        const bool more = (it + 1 < 16);
        if (more) {
            const int kvn = kvbase + (it + 1) * 64;
            nk0 = *(const bf16x8*)(Kh  + (size_t)(kvn + sr     ) * HDD + sc * 8);
            nk1 = *(const bf16x8*)(Kh  + (size_t)(kvn + sr + 32) * HDD + sc * 8);
            nv0 = *(const bf16x8*)(Vth + (size_t)(sr     ) * SS + kvn + sc * 8);
            nv1 = *(const bf16x8*)(Vth + (size_t)(sr + 32) * SS + kvn + sc * 8);
        }

        f32x16 sfr[2];
        __builtin_amdgcn_s_setprio(1);
        #pragma unroll
        for (int ni = 0; ni < 2; ni++) {
            #pragma unroll
            for (int r = 0; r < 16; r++) sfr[ni][r] = 0.f;
            #pragma unroll
            for (int f = 0; f < 4; f++) {
                bf16x8 kb = *reinterpret_cast<const bf16x8*>(
                    &Ks[(ko + (2 * f + ln5) * 65 + ni * 32 + ln31) * 8]);
                sfr[ni] = __builtin_amdgcn_mfma_f32_32x32x16_bf16(kb, aq[f], sfr[ni], 0, 0, 0);
            }
        }
        __builtin_amdgcn_s_setprio(0);

        float p[2][16];
        #pragma unroll
        for (int ni = 0; ni < 2; ni++)
            #pragma unroll
            for (int r = 0; r < 16; r++) {
                p[ni][r] = __builtin_amdgcn_exp2f(sfr[ni][r]);
                l += p[ni][r];
            }

        bf16x8 ap[4];
        #pragma unroll
        for (int c16 = 0; c16 < 4; c16++)
            #pragma unroll
            for (int j = 0; j < 8; j++)
                ap[c16][j] = (bf16_t)p[c16 >> 1][(c16 & 1) * 8 + j];

        __builtin_amdgcn_s_setprio(1);
        #pragma unroll
        for (int nh = 0; nh < 2; nh++) {
            const bf16_t* vrow = &Vs[vo + (nh * 32 + ln31) * 72];
            #pragma unroll
            for (int c16 = 0; c16 < 4; c16++) {
                bf16x8 vb = *reinterpret_cast<const bf16x8*>(vrow + c16 * 16 + 8 * ln5);
                o[nh] = __builtin_amdgcn_mfma_f32_32x32x16_bf16(ap[c16], vb, o[nh], 0, 0, 0);
            }
        }
        __builtin_amdgcn_s_setprio(0);

        if (more) {
            const int ko1 = (buf ^ 1) * 1040 + g * 520;
            const int vo1 = (buf ^ 1) * 9216 + g * 4608;
            *reinterpret_cast<bf16x8*>(&Ks[(ko1 + sc * 65 + sr     ) * 8]) = nk0;
            *reinterpret_cast<bf16x8*>(&Ks[(ko1 + sc * 65 + sr + 32) * 8]) = nk1;
            bf16_t* vd0 = &Vs[vo1 + (sr     ) * 72 + vcol];
            bf16_t* vd1 = &Vs[vo1 + (sr + 32) * 72 + vcol];
            *reinterpret_cast<bf16x4*>(vd0)     = __builtin_shufflevector(nv0, nv0, 0,1,2,3);
            *reinterpret_cast<bf16x4*>(vd0 + 8) = __builtin_shufflevector(nv0, nv0, 4,5,6,7);
            *reinterpret_cast<bf16x4*>(vd1)     = __builtin_shufflevector(nv1, nv1, 0,1,2,3);
            *reinterpret_cast<bf16x4*>(vd1 + 8) = __builtin_shufflevector(nv1, nv1, 4,5,6,7);
        }
        __syncthreads();
        buf ^= 1;
    }

    l += __shfl_xor(l, 32, 64);

    __syncthreads();
    float* Of = (float*)smem;
    float* Lf = (float*)(smem + 16384);
    if (ln5 == 0) Lf[g * 128 + wg * 32 + ln31] = l;
    if (g == 1) {
        #pragma unroll
        for (int nh = 0; nh < 2; nh++)
            #pragma unroll
            for (int r = 0; r < 16; r++) {
                const int q = (r & 3) + 8 * (r >> 2) + 4 * ln5;
                Of[(wg * 32 + q) * 64 + nh * 32 + ln31] = o[nh][r];
            }
    }
    __syncthreads();
    if (g == 0) {
        float inv[16];
        #pragma unroll
        for (int r = 0; r < 16; r++) {
            const int q = (r & 3) + 8 * (r >> 2) + 4 * ln5;
            inv[r] = 1.f / (Lf[wg * 32 + q] + Lf[128 + wg * 32 + q]);
        }
        #pragma unroll
        for (int nh = 0; nh < 2; nh++)
            #pragma unroll
            for (int r = 0; r < 16; r++) {
                const int q  = (r & 3) + 8 * (r >> 2) + 4 * ln5;
                const int hd = nh * 32 + ln31;
                float val = (o[nh][r] + Of[(wg * 32 + q) * 64 + hd]) * inv[r];
                ob[((size_t)b * SS + q0w + q) * DD + h * HDD + hd] = (bf16_t)val;
            }
    }
}

// ---------------------------------------------------------------------------
extern "C" void kernel_launch(void* const* d_in, const int* in_sizes, int n_in,
                              void* d_out, int out_size, void* d_ws, size_t ws_size,
                              hipStream_t stream) {
    const float* x     = (const float*)d_in[0];
    const float* Wqkv  = (const float*)d_in[1];
    const float* bqkv  = (const float*)d_in[2];
    const float* Wproj = (const float*)d_in[3];
    const float* bproj = (const float*)d_in[4];
    float* out = (float*)d_out;

    const size_t NEL = (size_t)MM * DD;   // 4194304
    bf16_t* qws    = (bf16_t*)d_ws;
    bf16_t* kws    = qws  + NEL;
    bf16_t* vtws   = kws  + NEL;
    bf16_t* xb     = vtws + NEL;          // aliased: xb then ows
    bf16_t* ows    = xb;
    bf16_t* wqkvt  = xb + NEL;
    bf16_t* wprojt = wqkvt + (size_t)NQKV * DD;

    prep<<<6144, 256, 0, stream>>>(x, Wqkv, Wproj, xb, wqkvt, wprojt);

    gemm_qkv<<<dim3(NQKV / 128, MM / 128), 512, 0, stream>>>(
        xb, wqkvt, bqkv, qws, kws, vtws);

    attn_kernel<<<dim3(SS / 128, BB * HH), 512, 0, stream>>>(qws, kws, vtws, ows);

    gemm_proj<<<dim3(DD / 128, MM / 128), 512, 0, stream>>>(
        ows, wprojt, bproj, out);
}